// Round 14
// baseline (319.039 us; speedup 1.0000x reference)
//
#include <hip/hip_runtime.h>
#include <math.h>

#define B_    8
#define N_TOK 3136
#define C_    384
#define DH    48
#define NK    784
#define HID   768
#define M1    25088
#define M2    6272
#define M1Q   6272      // quarter of M1

typedef unsigned short u16;
typedef __attribute__((ext_vector_type(8))) short bf16x8;
typedef __attribute__((ext_vector_type(4))) float f32x4;

__device__ __forceinline__ float b2f(u16 u) {
  return __uint_as_float(((unsigned)u) << 16);
}
__device__ __forceinline__ u16 f2b(float f) {
  unsigned u = __float_as_uint(f);
  return (u16)((u + 0x7fffu + ((u >> 16) & 1u)) >> 16);  // RNE
}
__device__ __forceinline__ void gload_lds16(const u16* g, u16* l) {
  __builtin_amdgcn_global_load_lds(
      (const __attribute__((address_space(1))) void*)g,
      (__attribute__((address_space(3))) void*)l, 16, 0, 0);
}
// RNE pack of two f32 into one dword of 2x bf16 (low=a, high=b). gfx950 has
// no builtin for v_cvt_pk_bf16_f32 (guide T12) -- inline asm, pure VALU op.
__device__ __forceinline__ unsigned cvtpk_bf16(float a, float b) {
  unsigned r;
  asm("v_cvt_pk_bf16_f32 %0, %1, %2" : "=v"(r) : "v"(a), "v"(b));
  return r;
}
// 2^x via the native trans op (input pre-scaled by log2e upstream).
__device__ __forceinline__ float exp2_fast(float x) {
  float r;
  asm("v_exp_f32 %0, %1" : "=v"(r) : "v"(x));
  return r;
}
// Bijective XCD-contiguous block remap (m204): hardware assigns block i to
// XCD i%8; this gives each XCD a CONTIGUOUS range of logical work ids, so
// blocks sharing an A panel land on the same XCD's L2.
__device__ __forceinline__ int xcd_swz(int blk, int nwg) {
  const int q = nwg >> 3, r = nwg & 7;
  const int x = blk & 7, j = blk >> 3;
  return (x < r ? x * (q + 1) : r * (q + 1) + (x - r) * q) + j;
}

// -------- Batched weight transpose args (merged into ln1_pool_tr) --------
struct TransArgs {
  const float* src[6];
  u16* dst[6];
  int K[6], N[6];
};

// --- Fused LN1 + pool + weight transposes (all independent; one launch) ---
// blocks [0, 6272): LayerNorm, 4 rows each (float2-vectorized).
// blocks [6272, 10976): 2x2 avg pool, 2 cols/thread.
// blocks [10976, 11264): 6 weight transpose+converts (64x64 tiles).
#define LN1B  (M1 / 4)                   // 6272
#define POOLB ((M2 * (C_ / 2)) / 256)    // 4704
#define TRB0  (LN1B + POOLB)             // 10976
__global__ __launch_bounds__(256) void ln1_pool_tr(
    const float* __restrict__ X, const float* __restrict__ w,
    const float* __restrict__ b, u16* __restrict__ Y, u16* __restrict__ KV,
    TransArgs ta) {
  __shared__ u16 tile[64][73];
  const int blk = blockIdx.x;
  if (blk < LN1B) {
    const int row = blk * 4 + (threadIdx.x >> 6);
    const int lane = threadIdx.x & 63;
    const float2* xp = (const float2*)(X + (size_t)row * C_);
    float2 vv[3];
#pragma unroll
    for (int i = 0; i < 3; ++i) vv[i] = xp[lane + 64 * i];
    float s = 0.f;
#pragma unroll
    for (int i = 0; i < 3; ++i) s += vv[i].x + vv[i].y;
#pragma unroll
    for (int off = 32; off > 0; off >>= 1) s += __shfl_xor(s, off);
    const float mu = s * (1.0f / C_);
    float q = 0.f;
#pragma unroll
    for (int i = 0; i < 3; ++i) {
      float dx = vv[i].x - mu, dy = vv[i].y - mu;
      q += dx * dx + dy * dy;
    }
#pragma unroll
    for (int off = 32; off > 0; off >>= 1) q += __shfl_xor(q, off);
    const float r = rsqrtf(q * (1.0f / C_) + 1e-6f);
    const float2* wp = (const float2*)w;
    const float2* bp = (const float2*)b;
#pragma unroll
    for (int i = 0; i < 3; ++i) {
      int cp = lane + 64 * i;
      float2 wv = wp[cp], bv = bp[cp];
      u16 o0 = f2b((vv[i].x - mu) * r * wv.x + bv.x);
      u16 o1 = f2b((vv[i].y - mu) * r * wv.y + bv.y);
      ushort2 o = {o0, o1};
      *(ushort2*)&Y[(size_t)row * C_ + cp * 2] = o;
    }
  } else if (blk < TRB0) {
    int t = (blk - LN1B) * 256 + threadIdx.x;  // pair index
    if (t >= M2 * (C_ / 2)) return;
    int cp = t % (C_ / 2);
    int row = t / (C_ / 2);
    int bb = row / NK;
    int rr = row - bb * NK;
    int hk = rr / 28;
    int wk = rr - hk * 28;
    const float* p = X + ((size_t)(bb * N_TOK + hk * 112 + wk * 2)) * C_ + cp * 2;
    float2 a0 = *(const float2*)(p);
    float2 a1 = *(const float2*)(p + C_);
    float2 a2 = *(const float2*)(p + 56 * C_);
    float2 a3 = *(const float2*)(p + 57 * C_);
    ushort2 o = {f2b(0.25f * (a0.x + a1.x + a2.x + a3.x)),
                 f2b(0.25f * (a0.y + a1.y + a2.y + a3.y))};
    *(ushort2*)&KV[(size_t)t * 2] = o;
  } else {
    // transpose blocks: id0..3 (384x384): 36 each; id4 (384x768): 72;
    // id5 (768x384): 72.
    const int tr = blk - TRB0;
    int id, bx, by;
    if (tr < 144)      { id = tr / 36; int rm = tr % 36; bx = rm % 6;  by = rm / 6; }
    else if (tr < 216) { id = 4;       int rm = tr - 144; bx = rm % 12; by = rm / 12; }
    else               { id = 5;       int rm = tr - 216; bx = rm % 6;  by = rm / 6; }
    const float* W = ta.src[id];
    u16* WT = ta.dst[id];
    const int K = ta.K[id], N = ta.N[id];
    const int k0 = by * 64, n0 = bx * 64;
    for (int i = threadIdx.x; i < 64 * 64; i += 256) {
      int kk = i >> 6, nn = i & 63;
      tile[kk][nn] = f2b(W[(size_t)(k0 + kk) * N + n0 + nn]);
    }
    __syncthreads();
    for (int i = threadIdx.x; i < 64 * 64; i += 256) {
      int nn = i >> 6, kk = i & 63;
      WT[(size_t)(n0 + nn) * K + k0 + kk] = tile[kk][nn];
    }
  }
}

// ---------------- MFMA GEMM core: C(m0..+128, n0..+128) ----------------
// oscale multiplies (acc + bias) before EPI transforms (used to fold the
// attention softmax scale * log2(e) into the Q projection; 1.0f elsewhere).
template<int EPI, bool RES32, bool OUT32>
__device__ __forceinline__ void gemm_core(
    const u16* __restrict__ A, const u16* __restrict__ BT,
    const float* __restrict__ bias, const void* __restrict__ resv,
    void* __restrict__ Cv, int N, int K, float oscale, int m0, int n0) {
  __shared__ u16 As[128 * 64];
  __shared__ u16 Bs[128 * 64];
  const int tid  = threadIdx.x;
  const int wave = tid >> 6;
  const int lane = tid & 63;
  const int quad = lane >> 4;
  const int ll   = lane & 15;
  const int wm   = wave >> 1, wn = wave & 1;

  const int srow = wave * 32 + (lane >> 3);
  const int sgs  = lane & 7;

  f32x4 acc[4][4];
#pragma unroll
  for (int i = 0; i < 4; ++i)
#pragma unroll
    for (int j = 0; j < 4; ++j) acc[i][j] = (f32x4){0.f, 0.f, 0.f, 0.f};

  for (int kk0 = 0; kk0 < K; kk0 += 64) {
    __syncthreads();
#pragma unroll
    for (int c = 0; c < 4; ++c) {
      const int r = srow + c * 8;
      const int g = sgs ^ (r & 7);
      gload_lds16(A  + (size_t)(m0 + r) * K + kk0 + g * 8,
                  As + (size_t)(wave * 32 + c * 8) * 64);
      gload_lds16(BT + (size_t)(n0 + r) * K + kk0 + g * 8,
                  Bs + (size_t)(wave * 32 + c * 8) * 64);
    }
    __syncthreads();
#pragma unroll
    for (int ks = 0; ks < 2; ++ks) {
      const int gsw = (quad + 4 * ks) ^ (ll & 7);
      bf16x8 af[4], bfr[4];
#pragma unroll
      for (int im = 0; im < 4; ++im)
        af[im] = *(const bf16x8*)&As[(size_t)(wm * 64 + im * 16 + ll) * 64 + gsw * 8];
#pragma unroll
      for (int jn = 0; jn < 4; ++jn)
        bfr[jn] = *(const bf16x8*)&Bs[(size_t)(wn * 64 + jn * 16 + ll) * 64 + gsw * 8];
#pragma unroll
      for (int im = 0; im < 4; ++im)
#pragma unroll
        for (int jn = 0; jn < 4; ++jn)
          acc[im][jn] = __builtin_amdgcn_mfma_f32_16x16x32_bf16(
              af[im], bfr[jn], acc[im][jn], 0, 0, 0);
    }
  }

  float bb[4];
#pragma unroll
  for (int jn = 0; jn < 4; ++jn) bb[jn] = bias[n0 + wn * 64 + jn * 16 + ll];
#pragma unroll
  for (int im = 0; im < 4; ++im) {
    const int row = m0 + wm * 64 + im * 16 + quad * 4;
#pragma unroll
    for (int jn = 0; jn < 4; ++jn) {
      const int col = n0 + wn * 64 + jn * 16 + ll;
#pragma unroll
      for (int r = 0; r < 4; ++r) {
        float o = (acc[im][jn][r] + bb[jn]) * oscale;
        if (EPI == 1) {
          o = 0.5f * o * (1.0f + erff(o * 0.70710678118654752f));
        } else if (EPI == 2) {
          size_t ri = (size_t)(row + r) * N + col;
          o += RES32 ? ((const float*)resv)[ri] : b2f(((const u16*)resv)[ri]);
        }
        if (OUT32) ((float*)Cv)[(size_t)(row + r) * N + col] = o;
        else       ((u16*)Cv)[(size_t)(row + r) * N + col] = f2b(o);
      }
    }
  }
}

// 1-D grid + bijective XCD swizzle; NX = N-tiles (x fastest -> A-panel
// sharers get consecutive logical ids -> same XCD).
template<int EPI, bool RES32, bool OUT32>
__global__ __launch_bounds__(256) void gemm_bt(
    const u16* __restrict__ A, const u16* __restrict__ BT,
    const float* __restrict__ bias, const void* __restrict__ resv,
    void* __restrict__ Cv, int N, int K, int NX) {
  const int flat = xcd_swz(blockIdx.x, gridDim.x);
  const int y = flat / NX, x = flat - y * NX;
  gemm_core<EPI, RES32, OUT32>(A, BT, bias, resv, Cv, N, K, 1.0f,
                               y << 7, x << 7);
}

// Q/K/V fused, exact-work 1-D grid (882 = Q:588 + KV:294 interleaved),
// XCD-swizzled. K and V blocks sharing an A(P)-panel are adjacent ids.
struct QKVArgs {
  const u16* A[3];
  const u16* BT[3];
  const float* bias[3];
  u16* C[3];
  float osc[3];
};
__global__ __launch_bounds__(256) void gemm_qkv(QKVArgs a) {
  const int flat = xcd_swz(blockIdx.x, gridDim.x);
  int z, y, x;
  if (flat < 588) {
    z = 0; y = flat / 3; x = flat - y * 3;
  } else {
    int p = flat - 588;              // 0..293: 49 panels x {K,V} x 3 cols
    y = p / 6;
    int t2 = p - y * 6;
    z = (t2 >= 3) ? 2 : 1;
    x = (t2 >= 3) ? t2 - 3 : t2;
  }
  gemm_core<0, false, false>(a.A[z], a.BT[z], a.bias[z], nullptr, a.C[z],
                             C_, C_, a.osc[z], y << 7, x << 7);
}

// ---- Wide-tile fc1 (R20): BM=128, BN=384, 512 thr; grid (2, M/128) ----
// Same staging/compute skeleton as proj_res_ln2 (verified). 3x fewer blocks
// than the 128x128 version; A panel staged once per 384 output cols.
__global__ __launch_bounds__(512) void gemm_fc1_wide(
    const u16* __restrict__ A, const u16* __restrict__ BT,
    const float* __restrict__ bias, u16* __restrict__ Cv) {
  __shared__ u16 As[128 * 64];   // 16 KB
  __shared__ u16 Bs[384 * 64];   // 48 KB
  const int tid  = threadIdx.x;
  const int wave = tid >> 6;
  const int lane = tid & 63;
  const int quad = lane >> 4;
  const int ll   = lane & 15;
  const int wm   = wave >> 2;        // 0..1  (64 rows each)
  const int wn   = wave & 3;         // 0..3  (96 cols each)
  const int m0   = blockIdx.y << 7;
  const int n0   = blockIdx.x * 384;

  const int srow = tid >> 3;                 // 0..63 within each 64-row chunk
  const int g    = (lane & 7) ^ (lane >> 3); // XOR-swizzled source group

  f32x4 acc[4][6];
#pragma unroll
  for (int i = 0; i < 4; ++i)
#pragma unroll
    for (int j = 0; j < 6; ++j) acc[i][j] = (f32x4){0.f, 0.f, 0.f, 0.f};

  for (int kk0 = 0; kk0 < C_; kk0 += 64) {
    __syncthreads();
#pragma unroll
    for (int i = 0; i < 8; ++i) {
      const int row = i * 64 + srow;
      if (i < 2) {
        gload_lds16(A + (size_t)(m0 + row) * C_ + kk0 + g * 8,
                    As + (size_t)(i * 64 + wave * 8) * 64);
      } else {
        gload_lds16(BT + (size_t)(n0 + row - 128) * C_ + kk0 + g * 8,
                    Bs + (size_t)((i - 2) * 64 + wave * 8) * 64);
      }
    }
    __syncthreads();
#pragma unroll
    for (int ks = 0; ks < 2; ++ks) {
      const int gsw = (quad + 4 * ks) ^ (ll & 7);
      bf16x8 af[4], bfr[6];
#pragma unroll
      for (int im = 0; im < 4; ++im)
        af[im] = *(const bf16x8*)&As[(size_t)(wm * 64 + im * 16 + ll) * 64 + gsw * 8];
#pragma unroll
      for (int jn = 0; jn < 6; ++jn)
        bfr[jn] = *(const bf16x8*)&Bs[(size_t)(wn * 96 + jn * 16 + ll) * 64 + gsw * 8];
#pragma unroll
      for (int im = 0; im < 4; ++im)
#pragma unroll
        for (int jn = 0; jn < 6; ++jn)
          acc[im][jn] = __builtin_amdgcn_mfma_f32_16x16x32_bf16(
              af[im], bfr[jn], acc[im][jn], 0, 0, 0);
    }
  }

  float bb[6];
#pragma unroll
  for (int jn = 0; jn < 6; ++jn) bb[jn] = bias[n0 + wn * 96 + jn * 16 + ll];
#pragma unroll
  for (int im = 0; im < 4; ++im) {
    const int rid = wm * 64 + im * 16 + quad * 4;
#pragma unroll
    for (int jn = 0; jn < 6; ++jn) {
      const int col = n0 + wn * 96 + jn * 16 + ll;
#pragma unroll
      for (int r = 0; r < 4; ++r) {
        float o = acc[im][jn][r] + bb[jn];
        o = 0.5f * o * (1.0f + erff(o * 0.70710678118654752f));
        Cv[(size_t)(m0 + rid + r) * HID + col] = f2b(o);
      }
    }
  }
}

// ------- Fused proj + residual + LN2 (R17): BM=128, BN=384 (full width) -----
// One block owns 128 full rows: x1 = x + attnO @ pw + pb -> T1 (bf16), then
// LN2(x1) -> T0 in the same kernel (row stats via one LDS partial exchange).
// No XCD swizzle: BN = full width -> each A panel read by exactly one block.
__global__ __launch_bounds__(512) void proj_res_ln2(
    const u16* A, const u16* __restrict__ BT,
    const float* __restrict__ bias, const float* __restrict__ xres,
    const float* __restrict__ w2, const float* __restrict__ b2,
    u16* __restrict__ X1, u16* Y) {
  __shared__ u16 As[128 * 64];   // 16 KB (reused as f32 partial buf in epilogue)
  __shared__ u16 Bs[384 * 64];   // 48 KB
  const int tid  = threadIdx.x;
  const int wave = tid >> 6;
  const int lane = tid & 63;
  const int quad = lane >> 4;
  const int ll   = lane & 15;
  const int wm   = wave >> 2;        // 0..1  (64 rows each)
  const int wn   = wave & 3;         // 0..3  (96 cols each)
  const int m0   = blockIdx.x << 7;

  const int srow = tid >> 3;                 // 0..63 within each 64-row chunk
  const int g    = (lane & 7) ^ (lane >> 3); // XOR-swizzled source group

  f32x4 acc[4][6];
#pragma unroll
  for (int i = 0; i < 4; ++i)
#pragma unroll
    for (int j = 0; j < 6; ++j) acc[i][j] = (f32x4){0.f, 0.f, 0.f, 0.f};

  for (int kk0 = 0; kk0 < 384; kk0 += 64) {
    __syncthreads();
    // stage 512 combined rows (A:0..127, B:0..383), 64 rows per chunk i
#pragma unroll
    for (int i = 0; i < 8; ++i) {
      const int row = i * 64 + srow;
      if (i < 2) {
        gload_lds16(A + (size_t)(m0 + row) * 384 + kk0 + g * 8,
                    As + (size_t)(i * 64 + wave * 8) * 64);
      } else {
        gload_lds16(BT + (size_t)(row - 128) * 384 + kk0 + g * 8,
                    Bs + (size_t)((i - 2) * 64 + wave * 8) * 64);
      }
    }
    __syncthreads();
#pragma unroll
    for (int ks = 0; ks < 2; ++ks) {
      const int gsw = (quad + 4 * ks) ^ (ll & 7);
      bf16x8 af[4], bfr[6];
#pragma unroll
      for (int im = 0; im < 4; ++im)
        af[im] = *(const bf16x8*)&As[(size_t)(wm * 64 + im * 16 + ll) * 64 + gsw * 8];
#pragma unroll
      for (int jn = 0; jn < 6; ++jn)
        bfr[jn] = *(const bf16x8*)&Bs[(size_t)(wn * 96 + jn * 16 + ll) * 64 + gsw * 8];
#pragma unroll
      for (int im = 0; im < 4; ++im)
#pragma unroll
        for (int jn = 0; jn < 6; ++jn)
          acc[im][jn] = __builtin_amdgcn_mfma_f32_16x16x32_bf16(
              af[im], bfr[jn], acc[im][jn], 0, 0, 0);
    }
  }

  // ---- epilogue phase 1: o = acc + bias + x residual; write X1; keep o ----
  float bb[6];
#pragma unroll
  for (int jn = 0; jn < 6; ++jn) bb[jn] = bias[wn * 96 + jn * 16 + ll];
  float ps[4][4], pq[4][4];
#pragma unroll
  for (int im = 0; im < 4; ++im)
#pragma unroll
    for (int r = 0; r < 4; ++r) { ps[im][r] = 0.f; pq[im][r] = 0.f; }
#pragma unroll
  for (int im = 0; im < 4; ++im) {
    const int rid = wm * 64 + im * 16 + quad * 4;
#pragma unroll
    for (int jn = 0; jn < 6; ++jn) {
      const int col = wn * 96 + jn * 16 + ll;
#pragma unroll
      for (int r = 0; r < 4; ++r) {
        float o = acc[im][jn][r] + bb[jn] +
                  xres[(size_t)(m0 + rid + r) * C_ + col];
        X1[(size_t)(m0 + rid + r) * C_ + col] = f2b(o);
        acc[im][jn][r] = o;
        ps[im][r] += o;
        pq[im][r] += o * o;
      }
    }
  }
  // reduce partials over the 16 ll lanes (rows are ll-invariant)
#pragma unroll
  for (int msk = 1; msk < 16; msk <<= 1)
#pragma unroll
    for (int im = 0; im < 4; ++im)
#pragma unroll
      for (int r = 0; r < 4; ++r) {
        ps[im][r] += __shfl_xor(ps[im][r], msk);
        pq[im][r] += __shfl_xor(pq[im][r], msk);
      }
  __syncthreads();                 // all LDS reads of K-loop done; reuse As
  float* pbuf = (float*)As;        // [128 rows][4 nwaves][2] = 4 KB
  float* rbm  = pbuf + 128 * 8;    // [128 rows][2] = 1 KB (mu, rinv)
  if (ll == 0) {
#pragma unroll
    for (int im = 0; im < 4; ++im)
#pragma unroll
      for (int r = 0; r < 4; ++r) {
        const int rid = wm * 64 + im * 16 + quad * 4 + r;
        float2 pr = {ps[im][r], pq[im][r]};
        *(float2*)&pbuf[rid * 8 + wn * 2] = pr;
      }
  }
  __syncthreads();
  if (tid < 128) {
    float s = 0.f, q = 0.f;
#pragma unroll
    for (int w = 0; w < 4; ++w) {
      float2 pr = *(float2*)&pbuf[tid * 8 + w * 2];
      s += pr.x; q += pr.y;
    }
    const float mu  = s * (1.0f / C_);
    const float var = q * (1.0f / C_) - mu * mu;
    float2 mr = {mu, rsqrtf(var + 1e-6f)};
    *(float2*)&rbm[tid * 2] = mr;
  }
  __syncthreads();
  // ---- epilogue phase 2: normalize + write Y ----
  float wc[6], bc[6];
#pragma unroll
  for (int jn = 0; jn < 6; ++jn) {
    const int col = wn * 96 + jn * 16 + ll;
    wc[jn] = w2[col]; bc[jn] = b2[col];
  }
#pragma unroll
  for (int im = 0; im < 4; ++im) {
    const int rid = wm * 64 + im * 16 + quad * 4;
#pragma unroll
    for (int r = 0; r < 4; ++r) {
      float2 mr = *(float2*)&rbm[(rid + r) * 2];
#pragma unroll
      for (int jn = 0; jn < 6; ++jn) {
        const int col = wn * 96 + jn * 16 + ll;
        Y[(size_t)(m0 + rid + r) * C_ + col] =
            f2b((acc[im][jn][r] - mr.x) * mr.y * wc[jn] + bc[jn]);
      }
    }
  }
}

// ---------------- MFMA flash attention (R19: K-clamp removed) ----------------
// Overflow K prefetch rows (784..831, only at t=11) land in the adjacent VB
// region (valid memory); the garbage S[1..3] at t=12 is provably unused
// (tail path computes exp2 only on S[0] = keys 768..783, genuine rows).
#define QS_STR 72
__global__ __launch_bounds__(512) void attn_mfma(
    const u16* __restrict__ Q, const u16* __restrict__ Kb,
    const u16* __restrict__ Vb, u16* __restrict__ O) {
  __shared__ u16 Ks[2][64 * 64];        // 16 KB  (swizzled, stride 64)
  __shared__ u16 Vt[2][48 * QS_STR];    // 13.5 KB (transposed, permuted cols)
  const int tid  = threadIdx.x;
  const int wave = tid >> 6;
  const int lane = tid & 63;
  const int quad = lane >> 4;
  const int ll   = lane & 15;
  // XCD swizzle: xcd = blk&7 owns orig in [xcd*200, xcd*200+200).
  const int blk  = blockIdx.x;
  const int orig = (blk & 7) * 200 + (blk >> 3);
  const int bh   = orig / 25;
  const int qt   = orig - bh * 25;
  const int b    = bh >> 3, h = bh & 7;
  const int q0   = qt * 128;

  // ---- Q fragments in registers (B-operand of swapped QK); pre-scaled
  // by d^-0.5 * log2e in the Q projection. Cols 48..63 zero-padded.
  bf16x8 qf0, qf1;
  {
    int qrow = q0 + wave * 16 + ll;
    if (qrow >= N_TOK) qrow = N_TOK - 1;       // rows masked at output
    const u16* qp = Q + ((size_t)(b * N_TOK) + qrow) * C_ + h * DH;
    qf0 = *(const bf16x8*)(qp + quad * 8);                    // c = quad*8..+8
    if (quad < 2) qf1 = *(const bf16x8*)(qp + 32 + quad * 8); // c = 32..48
    else          qf1 = (bf16x8){0, 0, 0, 0, 0, 0, 0, 0};     // c = 48..64 pad
  }

  // K tile prefetch: pre-swizzled global source, linear LDS dest (m173).
  const int krow = (wave << 3) + (lane >> 3);          // tile row 0..63
  const int kgrp = (lane & 7) ^ (lane >> 3);           // group g = slot ^ (row&7)
  const size_t kbase_g = (size_t)(b * NK) * C_ + h * DH + kgrp * 8;

  // V staging: column permutation pcol = sigma^{-1}:
  // key = nt*16 + qp*4 + r  ->  (nt>>1)*32 + qp*8 + (nt&1)*4 + r
  uint4 vreg;
  const int vkey  = lane;
  const int vcol  = ((vkey >> 5) << 5) + (((vkey & 15) >> 2) << 3) +
                    (((vkey >> 4) & 1) << 2) + (vkey & 3);

  // ---- prologue: stage tile 0 ----
  {
    gload_lds16(Kb + kbase_g + (size_t)krow * C_, &Ks[0][wave << 9]);
    if (wave < 6) {
      vreg = *(const uint4*)(Vb + ((size_t)(b * NK) + vkey) * C_ + h * DH + wave * 8);
      const u16* vp = (const u16*)&vreg;
#pragma unroll
      for (int j = 0; j < 8; ++j)
        Vt[0][(wave * 8 + j) * QS_STR + vcol] = vp[j];
    }
  }
  __syncthreads();

  f32x4 Ofr[3] = {{0.f,0.f,0.f,0.f},{0.f,0.f,0.f,0.f},{0.f,0.f,0.f,0.f}};
  f32x4 Sden = {0.f, 0.f, 0.f, 0.f};
  const short oneb = (short)0x3F80;   // bf16 1.0
  const bf16x8 ones = {oneb, oneb, oneb, oneb, oneb, oneb, oneb, oneb};

  for (int t = 0; t < 13; ++t) {
    const int cur = t & 1, nxt = cur ^ 1;

    // -- issue next-tile loads first; latency hides under QK+softmax+PV --
    if (t < 12) {
      const int knext = (t + 1) * 64;
      gload_lds16(Kb + kbase_g + (size_t)(knext + krow) * C_, &Ks[nxt][wave << 9]);
      if (wave < 6) {
        int vk = knext + vkey; if (vk >= NK) vk = NK - 1;   // keep: P=0*NaN hazard
        vreg = *(const uint4*)(Vb + ((size_t)(b * NK) + vk) * C_ + h * DH + wave * 8);
      }
    }

    // -- swapped QK^T: S^T[key][qrow], A = K fragments from LDS, B = Q regs --
    f32x4 S[4];
    __builtin_amdgcn_s_setprio(1);
#pragma unroll
    for (int nt = 0; nt < 4; ++nt) {
      const int rb = (nt * 16 + ll) * 64;
      bf16x8 k0f = *(const bf16x8*)&Ks[cur][rb + ((quad    ) ^ (ll & 7)) * 8];
      bf16x8 k1f = *(const bf16x8*)&Ks[cur][rb + ((quad + 4) ^ (ll & 7)) * 8];
      f32x4 acc = {0.f, 0.f, 0.f, 0.f};
      acc = __builtin_amdgcn_mfma_f32_16x16x32_bf16(k0f, qf0, acc, 0, 0, 0);
      acc = __builtin_amdgcn_mfma_f32_16x16x32_bf16(k1f, qf1, acc, 0, 0, 0);
      S[nt] = acc;
    }
    __builtin_amdgcn_s_setprio(0);

    // -- exp2 + RNE pack into PV A-frags. Keys per lane ARE the fragment.
    // Tiles 0..11 fully valid; tile 12 (keys 768..831): valid iff nt==0.
    unsigned pw[8];
    if (t != 12) {
#pragma unroll
      for (int nt = 0; nt < 4; ++nt)
#pragma unroll
        for (int rr = 0; rr < 2; ++rr)
          pw[nt * 2 + rr] =
              cvtpk_bf16(exp2_fast(S[nt][rr * 2]), exp2_fast(S[nt][rr * 2 + 1]));
    } else {
#pragma unroll
      for (int rr = 0; rr < 2; ++rr)
        pw[rr] = cvtpk_bf16(exp2_fast(S[0][rr * 2]), exp2_fast(S[0][rr * 2 + 1]));
#pragma unroll
      for (int i = 2; i < 8; ++i) pw[i] = 0u;
    }
    union PU { unsigned w[4]; bf16x8 v; };
    PU pk0, pk1;
#pragma unroll
    for (int i = 0; i < 4; ++i) { pk0.w[i] = pw[i]; pk1.w[i] = pw[4 + i]; }

    __builtin_amdgcn_s_setprio(1);
    // -- denominator: row sums via ones-MFMA (matrix pipe, not VALU) --
    Sden = __builtin_amdgcn_mfma_f32_16x16x32_bf16(pk0.v, ones, Sden, 0, 0, 0);
    Sden = __builtin_amdgcn_mfma_f32_16x16x32_bf16(pk1.v, ones, Sden, 0, 0, 0);

    // -- PV: B = V fragments from permuted-column Vt --
#pragma unroll
    for (int dt = 0; dt < 3; ++dt) {
      bf16x8 v0 = *(const bf16x8*)&Vt[cur][(dt * 16 + ll) * QS_STR + quad * 8];
      bf16x8 v1 = *(const bf16x8*)&Vt[cur][(dt * 16 + ll) * QS_STR + 32 + quad * 8];
      Ofr[dt] = __builtin_amdgcn_mfma_f32_16x16x32_bf16(pk0.v, v0, Ofr[dt], 0, 0, 0);
      Ofr[dt] = __builtin_amdgcn_mfma_f32_16x16x32_bf16(pk1.v, v1, Ofr[dt], 0, 0, 0);
    }
    __builtin_amdgcn_s_setprio(0);

    // -- land V regs into Vt[nxt] (auto vmcnt wait on vreg use) --
    if (t < 12 && wave < 6) {
      const u16* vp = (const u16*)&vreg;
#pragma unroll
      for (int j = 0; j < 8; ++j)
        Vt[nxt][(wave * 8 + j) * QS_STR + vcol] = vp[j];
    }
    // One barrier/iter: its vmcnt(0)+lgkmcnt(0) drain also retires the
    // K global_load_lds (in flight during the whole compute phase).
    __syncthreads();
  }

  // Sden[r] = denominator for qrow quad*4+r (same value in every ll lane).
  float inv[4];
#pragma unroll
  for (int r = 0; r < 4; ++r) inv[r] = 1.0f / Sden[r];
#pragma unroll
  for (int dt = 0; dt < 3; ++dt)
#pragma unroll
    for (int r = 0; r < 4; ++r) {
      int qrow = q0 + wave * 16 + quad * 4 + r;
      if (qrow < N_TOK)
        O[((size_t)b * N_TOK + qrow) * C_ + h * DH + dt * 16 + ll] =
            f2b(Ofr[dt][r] * inv[r]);
    }
}

// ---------------- Diagnostics ----------------
__global__ __launch_bounds__(256) void marker_fill(
    float* __restrict__ out, size_t n, float val) {
  size_t i = (size_t)blockIdx.x * 256 + threadIdx.x;
  const size_t stride = (size_t)gridDim.x * 256;
  for (; i < n; i += stride) out[i] = 0.f;
  if (blockIdx.x == 0 && threadIdx.x == 0) out[0] = val;
}

// ---------------- launch ----------------
extern "C" void kernel_launch(void* const* d_in, const int* in_sizes, int n_in,
                              void* d_out, int out_size, void* d_ws, size_t ws_size,
                              hipStream_t stream) {
  const float* x    = (const float*)d_in[0];
  const float* ln1w = (const float*)d_in[1];
  const float* ln1b = (const float*)d_in[2];
  const float* qw   = (const float*)d_in[3];
  const float* qb   = (const float*)d_in[4];
  const float* kw   = (const float*)d_in[5];
  const float* kb   = (const float*)d_in[6];
  const float* vw   = (const float*)d_in[7];
  const float* vb   = (const float*)d_in[8];
  const float* pw   = (const float*)d_in[9];
  const float* pb   = (const float*)d_in[10];
  const float* ln2w = (const float*)d_in[11];
  const float* ln2b = (const float*)d_in[12];
  const float* fc1w = (const float*)d_in[13];
  const float* fc1b = (const float*)d_in[14];
  const float* fc2w = (const float*)d_in[15];
  const float* fc2b = (const float*)d_in[16];

  const size_t BUF = (size_t)M1 * C_;
  float* outf = (float*)d_out;

  {
    static const int exp_sizes[19] = {
      M1 * C_, C_, C_, C_ * C_, C_, C_ * C_, C_, C_ * C_, C_, C_ * C_, C_,
      C_, C_, C_ * HID, HID, HID * C_, C_, 1, 1};
    int bad = -1;
    if (n_in != 19) bad = 99;
    else {
      for (int i = 0; i < 19; ++i)
        if (in_sizes[i] != exp_sizes[i]) { bad = i; break; }
    }
    if (bad >= 0) {
      marker_fill<<<1024, 256, 0, stream>>>(outf, BUF, 10000.0f + (float)bad);
      return;
    }
  }
  const size_t need_min  = 4096 + 3 * BUF * sizeof(u16);                     // 57.8 MB
  const size_t need_full = 4096 + (3 * BUF + (size_t)M1 * HID) * sizeof(u16); // 96.4 MB
  if (ws_size < need_min) {
    marker_fill<<<1024, 256, 0, stream>>>(outf, BUF, 30000.0f + (float)(ws_size >> 20));
    return;
  }
  const bool full_mlp = (ws_size >= need_full);

  u16* T0 = (u16*)((char*)d_ws + 4096);
  u16* T1 = T0 + BUF;
  u16* U  = T1 + BUF;
  u16* P  = U;
  u16* KB = U + (size_t)M2 * C_;
  u16* VB = U + (size_t)2 * M2 * C_;
  u16* HBq = U;                              // quarter-HB fallback overlay
  u16* HBfull = U + BUF;                     // full-M HB (only if full_mlp)
  u16* WTb = U + BUF - (size_t)(4 * C_ * C_ + 2 * C_ * HID);
  u16* wtq = WTb;
  u16* wtk = wtq + C_ * C_;
  u16* wtv = wtk + C_ * C_;
  u16* wtp = wtv + C_ * C_;
  u16* wtf1 = wtp + C_ * C_;
  u16* wtf2 = wtf1 + (size_t)C_ * HID;

  // 0+1. Fused LN1 + pool + all six weight transposes (one launch).
  {
    TransArgs ta;
    ta.src[0] = qw;   ta.dst[0] = wtq;  ta.K[0] = C_;  ta.N[0] = C_;
    ta.src[1] = kw;   ta.dst[1] = wtk;  ta.K[1] = C_;  ta.N[1] = C_;
    ta.src[2] = vw;   ta.dst[2] = wtv;  ta.K[2] = C_;  ta.N[2] = C_;
    ta.src[3] = pw;   ta.dst[3] = wtp;  ta.K[3] = C_;  ta.N[3] = C_;
    ta.src[4] = fc1w; ta.dst[4] = wtf1; ta.K[4] = C_;  ta.N[4] = HID;
    ta.src[5] = fc2w; ta.dst[5] = wtf2; ta.K[5] = HID; ta.N[5] = C_;
    ln1_pool_tr<<<TRB0 + 288, 256, 0, stream>>>(x, ln1w, ln1b, T0, P, ta);
  }

  // 2. Q/K/V projections, exact-work XCD-swizzled grid (882 blocks).
  {
    QKVArgs qa;
    qa.A[0] = T0; qa.BT[0] = wtq; qa.bias[0] = qb; qa.C[0] = T1;
    qa.A[1] = P;  qa.BT[1] = wtk; qa.bias[1] = kb; qa.C[1] = KB;
    qa.A[2] = P;  qa.BT[2] = wtv; qa.bias[2] = vb; qa.C[2] = VB;
    qa.osc[0] = 0.20823509507f;  // d^-0.5 * log2(e)
    qa.osc[1] = 1.0f;
    qa.osc[2] = 1.0f;
    gemm_qkv<<<dim3(882), 256, 0, stream>>>(qa);
  }

  // 3. MFMA flash attention -> T0  (1600 blocks, XCD-swizzled 1-D grid)
  attn_mfma<<<dim3(1600), 512, 0, stream>>>(T1, KB, VB, T0);

  // 4+5 fused. x1 = x + T0 @ pw + pb -> T1; LN2(x1) -> T0.
  proj_res_ln2<<<dim3(196), 512, 0, stream>>>(
      T0, wtp, pb, x, ln2w, ln2b, T1, T0);

  // 6/7. MLP. fc1 wide-tile (R20): grid (2, M/128), 392 blocks full path.
  if (full_mlp) {
    gemm_fc1_wide<<<dim3(2, 196), 512, 0, stream>>>(T0, wtf1, fc1b, HBfull);
    gemm_bt<2, false, true><<<dim3(588), 256, 0, stream>>>(
        HBfull, wtf2, fc2b, T1, outf, C_, HID, 3);
  } else {
    for (int qtr = 0; qtr < 4; ++qtr) {
      const size_t ro = (size_t)qtr * M1Q;
      gemm_fc1_wide<<<dim3(2, 49), 512, 0, stream>>>(
          T0 + ro * C_, wtf1, fc1b, HBq);
      gemm_bt<2, false, true><<<dim3(147), 256, 0, stream>>>(
          HBq, wtf2, fc2b, T1 + ro * C_, outf + ro * C_, C_, HID, 3);
    }
  }
}

// Round 18
// 305.554 us; speedup vs baseline: 1.0441x; 1.0441x over previous
//
#include <hip/hip_runtime.h>
#include <math.h>

#define B_    8
#define N_TOK 3136
#define C_    384
#define DH    48
#define NK    784
#define HID   768
#define M1    25088
#define M2    6272
#define M1Q   6272      // quarter of M1

typedef unsigned short u16;
typedef __attribute__((ext_vector_type(8))) short bf16x8;
typedef __attribute__((ext_vector_type(4))) float f32x4;

__device__ __forceinline__ float b2f(u16 u) {
  return __uint_as_float(((unsigned)u) << 16);
}
__device__ __forceinline__ u16 f2b(float f) {
  unsigned u = __float_as_uint(f);
  return (u16)((u + 0x7fffu + ((u >> 16) & 1u)) >> 16);  // RNE
}
__device__ __forceinline__ void gload_lds16(const u16* g, u16* l) {
  __builtin_amdgcn_global_load_lds(
      (const __attribute__((address_space(1))) void*)g,
      (__attribute__((address_space(3))) void*)l, 16, 0, 0);
}
// RNE pack of two f32 into one dword of 2x bf16 (low=a, high=b). gfx950 has
// no builtin for v_cvt_pk_bf16_f32 (guide T12) -- inline asm, pure VALU op.
__device__ __forceinline__ unsigned cvtpk_bf16(float a, float b) {
  unsigned r;
  asm("v_cvt_pk_bf16_f32 %0, %1, %2" : "=v"(r) : "v"(a), "v"(b));
  return r;
}
// 2^x via the native trans op (input pre-scaled by log2e upstream).
__device__ __forceinline__ float exp2_fast(float x) {
  float r;
  asm("v_exp_f32 %0, %1" : "=v"(r) : "v"(x));
  return r;
}
// Bijective XCD-contiguous block remap (m204): hardware assigns block i to
// XCD i%8; this gives each XCD a CONTIGUOUS range of logical work ids, so
// blocks sharing an A panel land on the same XCD's L2.
__device__ __forceinline__ int xcd_swz(int blk, int nwg) {
  const int q = nwg >> 3, r = nwg & 7;
  const int x = blk & 7, j = blk >> 3;
  return (x < r ? x * (q + 1) : r * (q + 1) + (x - r) * q) + j;
}

// -------- Batched weight transpose args (merged into ln1_pool_tr) --------
struct TransArgs {
  const float* src[6];
  u16* dst[6];
  int K[6], N[6];
};

// --- Fused LN1 + pool + weight transposes (all independent; one launch) ---
// blocks [0, 6272): LayerNorm, 4 rows each (float2-vectorized).
// blocks [6272, 10976): 2x2 avg pool, 2 cols/thread.
// blocks [10976, 11264): 6 weight transpose+converts (64x64 tiles).
#define LN1B  (M1 / 4)                   // 6272
#define POOLB ((M2 * (C_ / 2)) / 256)    // 4704
#define TRB0  (LN1B + POOLB)             // 10976
__global__ __launch_bounds__(256) void ln1_pool_tr(
    const float* __restrict__ X, const float* __restrict__ w,
    const float* __restrict__ b, u16* __restrict__ Y, u16* __restrict__ KV,
    TransArgs ta) {
  __shared__ u16 tile[64][73];
  const int blk = blockIdx.x;
  if (blk < LN1B) {
    const int row = blk * 4 + (threadIdx.x >> 6);
    const int lane = threadIdx.x & 63;
    const float2* xp = (const float2*)(X + (size_t)row * C_);
    float2 vv[3];
#pragma unroll
    for (int i = 0; i < 3; ++i) vv[i] = xp[lane + 64 * i];
    float s = 0.f;
#pragma unroll
    for (int i = 0; i < 3; ++i) s += vv[i].x + vv[i].y;
#pragma unroll
    for (int off = 32; off > 0; off >>= 1) s += __shfl_xor(s, off);
    const float mu = s * (1.0f / C_);
    float q = 0.f;
#pragma unroll
    for (int i = 0; i < 3; ++i) {
      float dx = vv[i].x - mu, dy = vv[i].y - mu;
      q += dx * dx + dy * dy;
    }
#pragma unroll
    for (int off = 32; off > 0; off >>= 1) q += __shfl_xor(q, off);
    const float r = rsqrtf(q * (1.0f / C_) + 1e-6f);
    const float2* wp = (const float2*)w;
    const float2* bp = (const float2*)b;
#pragma unroll
    for (int i = 0; i < 3; ++i) {
      int cp = lane + 64 * i;
      float2 wv = wp[cp], bv = bp[cp];
      u16 o0 = f2b((vv[i].x - mu) * r * wv.x + bv.x);
      u16 o1 = f2b((vv[i].y - mu) * r * wv.y + bv.y);
      ushort2 o = {o0, o1};
      *(ushort2*)&Y[(size_t)row * C_ + cp * 2] = o;
    }
  } else if (blk < TRB0) {
    int t = (blk - LN1B) * 256 + threadIdx.x;  // pair index
    if (t >= M2 * (C_ / 2)) return;
    int cp = t % (C_ / 2);
    int row = t / (C_ / 2);
    int bb = row / NK;
    int rr = row - bb * NK;
    int hk = rr / 28;
    int wk = rr - hk * 28;
    const float* p = X + ((size_t)(bb * N_TOK + hk * 112 + wk * 2)) * C_ + cp * 2;
    float2 a0 = *(const float2*)(p);
    float2 a1 = *(const float2*)(p + C_);
    float2 a2 = *(const float2*)(p + 56 * C_);
    float2 a3 = *(const float2*)(p + 57 * C_);
    ushort2 o = {f2b(0.25f * (a0.x + a1.x + a2.x + a3.x)),
                 f2b(0.25f * (a0.y + a1.y + a2.y + a3.y))};
    *(ushort2*)&KV[(size_t)t * 2] = o;
  } else {
    // transpose blocks: id0..3 (384x384): 36 each; id4 (384x768): 72;
    // id5 (768x384): 72.
    const int tr = blk - TRB0;
    int id, bx, by;
    if (tr < 144)      { id = tr / 36; int rm = tr % 36; bx = rm % 6;  by = rm / 6; }
    else if (tr < 216) { id = 4;       int rm = tr - 144; bx = rm % 12; by = rm / 12; }
    else               { id = 5;       int rm = tr - 216; bx = rm % 6;  by = rm / 6; }
    const float* W = ta.src[id];
    u16* WT = ta.dst[id];
    const int K = ta.K[id], N = ta.N[id];
    const int k0 = by * 64, n0 = bx * 64;
    for (int i = threadIdx.x; i < 64 * 64; i += 256) {
      int kk = i >> 6, nn = i & 63;
      tile[kk][nn] = f2b(W[(size_t)(k0 + kk) * N + n0 + nn]);
    }
    __syncthreads();
    for (int i = threadIdx.x; i < 64 * 64; i += 256) {
      int nn = i >> 6, kk = i & 63;
      WT[(size_t)(n0 + nn) * K + k0 + kk] = tile[kk][nn];
    }
  }
}

// ---------------- MFMA GEMM core: C(m0..+128, n0..+128) ----------------
// oscale multiplies (acc + bias) before EPI transforms (used to fold the
// attention softmax scale * log2(e) into the Q projection; 1.0f elsewhere).
template<int EPI, bool RES32, bool OUT32>
__device__ __forceinline__ void gemm_core(
    const u16* __restrict__ A, const u16* __restrict__ BT,
    const float* __restrict__ bias, const void* __restrict__ resv,
    void* __restrict__ Cv, int N, int K, float oscale, int m0, int n0) {
  __shared__ u16 As[128 * 64];
  __shared__ u16 Bs[128 * 64];
  const int tid  = threadIdx.x;
  const int wave = tid >> 6;
  const int lane = tid & 63;
  const int quad = lane >> 4;
  const int ll   = lane & 15;
  const int wm   = wave >> 1, wn = wave & 1;

  const int srow = wave * 32 + (lane >> 3);
  const int sgs  = lane & 7;

  f32x4 acc[4][4];
#pragma unroll
  for (int i = 0; i < 4; ++i)
#pragma unroll
    for (int j = 0; j < 4; ++j) acc[i][j] = (f32x4){0.f, 0.f, 0.f, 0.f};

  for (int kk0 = 0; kk0 < K; kk0 += 64) {
    __syncthreads();
#pragma unroll
    for (int c = 0; c < 4; ++c) {
      const int r = srow + c * 8;
      const int g = sgs ^ (r & 7);
      gload_lds16(A  + (size_t)(m0 + r) * K + kk0 + g * 8,
                  As + (size_t)(wave * 32 + c * 8) * 64);
      gload_lds16(BT + (size_t)(n0 + r) * K + kk0 + g * 8,
                  Bs + (size_t)(wave * 32 + c * 8) * 64);
    }
    __syncthreads();
#pragma unroll
    for (int ks = 0; ks < 2; ++ks) {
      const int gsw = (quad + 4 * ks) ^ (ll & 7);
      bf16x8 af[4], bfr[4];
#pragma unroll
      for (int im = 0; im < 4; ++im)
        af[im] = *(const bf16x8*)&As[(size_t)(wm * 64 + im * 16 + ll) * 64 + gsw * 8];
#pragma unroll
      for (int jn = 0; jn < 4; ++jn)
        bfr[jn] = *(const bf16x8*)&Bs[(size_t)(wn * 64 + jn * 16 + ll) * 64 + gsw * 8];
#pragma unroll
      for (int im = 0; im < 4; ++im)
#pragma unroll
        for (int jn = 0; jn < 4; ++jn)
          acc[im][jn] = __builtin_amdgcn_mfma_f32_16x16x32_bf16(
              af[im], bfr[jn], acc[im][jn], 0, 0, 0);
    }
  }

  float bb[4];
#pragma unroll
  for (int jn = 0; jn < 4; ++jn) bb[jn] = bias[n0 + wn * 64 + jn * 16 + ll];
#pragma unroll
  for (int im = 0; im < 4; ++im) {
    const int row = m0 + wm * 64 + im * 16 + quad * 4;
#pragma unroll
    for (int jn = 0; jn < 4; ++jn) {
      const int col = n0 + wn * 64 + jn * 16 + ll;
#pragma unroll
      for (int r = 0; r < 4; ++r) {
        float o = (acc[im][jn][r] + bb[jn]) * oscale;
        if (EPI == 1) {
          o = 0.5f * o * (1.0f + erff(o * 0.70710678118654752f));
        } else if (EPI == 2) {
          size_t ri = (size_t)(row + r) * N + col;
          o += RES32 ? ((const float*)resv)[ri] : b2f(((const u16*)resv)[ri]);
        }
        if (OUT32) ((float*)Cv)[(size_t)(row + r) * N + col] = o;
        else       ((u16*)Cv)[(size_t)(row + r) * N + col] = f2b(o);
      }
    }
  }
}

// 1-D grid + bijective XCD swizzle; NX = N-tiles (x fastest -> A-panel
// sharers get consecutive logical ids -> same XCD).
template<int EPI, bool RES32, bool OUT32>
__global__ __launch_bounds__(256) void gemm_bt(
    const u16* __restrict__ A, const u16* __restrict__ BT,
    const float* __restrict__ bias, const void* __restrict__ resv,
    void* __restrict__ Cv, int N, int K, int NX) {
  const int flat = xcd_swz(blockIdx.x, gridDim.x);
  const int y = flat / NX, x = flat - y * NX;
  gemm_core<EPI, RES32, OUT32>(A, BT, bias, resv, Cv, N, K, 1.0f,
                               y << 7, x << 7);
}

// Q/K/V fused, exact-work 1-D grid (882 = Q:588 + KV:294 interleaved),
// XCD-swizzled. K and V blocks sharing an A(P)-panel are adjacent ids.
struct QKVArgs {
  const u16* A[3];
  const u16* BT[3];
  const float* bias[3];
  u16* C[3];
  float osc[3];
};
__global__ __launch_bounds__(256) void gemm_qkv(QKVArgs a) {
  const int flat = xcd_swz(blockIdx.x, gridDim.x);
  int z, y, x;
  if (flat < 588) {
    z = 0; y = flat / 3; x = flat - y * 3;
  } else {
    int p = flat - 588;              // 0..293: 49 panels x {K,V} x 3 cols
    y = p / 6;
    int t2 = p - y * 6;
    z = (t2 >= 3) ? 2 : 1;
    x = (t2 >= 3) ? t2 - 3 : t2;
  }
  gemm_core<0, false, false>(a.A[z], a.BT[z], a.bias[z], nullptr, a.C[z],
                             C_, C_, a.osc[z], y << 7, x << 7);
}

// ------- Fused proj + residual + LN2 (R17): BM=128, BN=384 (full width) -----
// One block owns 128 full rows: x1 = x + attnO @ pw + pb -> T1 (bf16), then
// LN2(x1) -> T0 in the same kernel (row stats via one LDS partial exchange).
// No XCD swizzle: BN = full width -> each A panel read by exactly one block.
// Grid 196 <= 256 CUs -> single dispatch wave (why wide works HERE only).
__global__ __launch_bounds__(512) void proj_res_ln2(
    const u16* A, const u16* __restrict__ BT,
    const float* __restrict__ bias, const float* __restrict__ xres,
    const float* __restrict__ w2, const float* __restrict__ b2,
    u16* __restrict__ X1, u16* Y) {
  __shared__ u16 As[128 * 64];   // 16 KB (reused as f32 partial buf in epilogue)
  __shared__ u16 Bs[384 * 64];   // 48 KB
  const int tid  = threadIdx.x;
  const int wave = tid >> 6;
  const int lane = tid & 63;
  const int quad = lane >> 4;
  const int ll   = lane & 15;
  const int wm   = wave >> 2;        // 0..1  (64 rows each)
  const int wn   = wave & 3;         // 0..3  (96 cols each)
  const int m0   = blockIdx.x << 7;

  const int srow = tid >> 3;                 // 0..63 within each 64-row chunk
  const int g    = (lane & 7) ^ (lane >> 3); // XOR-swizzled source group

  f32x4 acc[4][6];
#pragma unroll
  for (int i = 0; i < 4; ++i)
#pragma unroll
    for (int j = 0; j < 6; ++j) acc[i][j] = (f32x4){0.f, 0.f, 0.f, 0.f};

  for (int kk0 = 0; kk0 < 384; kk0 += 64) {
    __syncthreads();
    // stage 512 combined rows (A:0..127, B:0..383), 64 rows per chunk i
#pragma unroll
    for (int i = 0; i < 8; ++i) {
      const int row = i * 64 + srow;
      if (i < 2) {
        gload_lds16(A + (size_t)(m0 + row) * 384 + kk0 + g * 8,
                    As + (size_t)(i * 64 + wave * 8) * 64);
      } else {
        gload_lds16(BT + (size_t)(row - 128) * 384 + kk0 + g * 8,
                    Bs + (size_t)((i - 2) * 64 + wave * 8) * 64);
      }
    }
    __syncthreads();
#pragma unroll
    for (int ks = 0; ks < 2; ++ks) {
      const int gsw = (quad + 4 * ks) ^ (ll & 7);
      bf16x8 af[4], bfr[6];
#pragma unroll
      for (int im = 0; im < 4; ++im)
        af[im] = *(const bf16x8*)&As[(size_t)(wm * 64 + im * 16 + ll) * 64 + gsw * 8];
#pragma unroll
      for (int jn = 0; jn < 6; ++jn)
        bfr[jn] = *(const bf16x8*)&Bs[(size_t)(wn * 96 + jn * 16 + ll) * 64 + gsw * 8];
#pragma unroll
      for (int im = 0; im < 4; ++im)
#pragma unroll
        for (int jn = 0; jn < 6; ++jn)
          acc[im][jn] = __builtin_amdgcn_mfma_f32_16x16x32_bf16(
              af[im], bfr[jn], acc[im][jn], 0, 0, 0);
    }
  }

  // ---- epilogue phase 1: o = acc + bias + x residual; write X1; keep o ----
  float bb[6];
#pragma unroll
  for (int jn = 0; jn < 6; ++jn) bb[jn] = bias[wn * 96 + jn * 16 + ll];
  float ps[4][4], pq[4][4];
#pragma unroll
  for (int im = 0; im < 4; ++im)
#pragma unroll
    for (int r = 0; r < 4; ++r) { ps[im][r] = 0.f; pq[im][r] = 0.f; }
#pragma unroll
  for (int im = 0; im < 4; ++im) {
    const int rid = wm * 64 + im * 16 + quad * 4;
#pragma unroll
    for (int jn = 0; jn < 6; ++jn) {
      const int col = wn * 96 + jn * 16 + ll;
#pragma unroll
      for (int r = 0; r < 4; ++r) {
        float o = acc[im][jn][r] + bb[jn] +
                  xres[(size_t)(m0 + rid + r) * C_ + col];
        X1[(size_t)(m0 + rid + r) * C_ + col] = f2b(o);
        acc[im][jn][r] = o;
        ps[im][r] += o;
        pq[im][r] += o * o;
      }
    }
  }
  // reduce partials over the 16 ll lanes (rows are ll-invariant)
#pragma unroll
  for (int msk = 1; msk < 16; msk <<= 1)
#pragma unroll
    for (int im = 0; im < 4; ++im)
#pragma unroll
      for (int r = 0; r < 4; ++r) {
        ps[im][r] += __shfl_xor(ps[im][r], msk);
        pq[im][r] += __shfl_xor(pq[im][r], msk);
      }
  __syncthreads();                 // all LDS reads of K-loop done; reuse As
  float* pbuf = (float*)As;        // [128 rows][4 nwaves][2] = 4 KB
  float* rbm  = pbuf + 128 * 8;    // [128 rows][2] = 1 KB (mu, rinv)
  if (ll == 0) {
#pragma unroll
    for (int im = 0; im < 4; ++im)
#pragma unroll
      for (int r = 0; r < 4; ++r) {
        const int rid = wm * 64 + im * 16 + quad * 4 + r;
        float2 pr = {ps[im][r], pq[im][r]};
        *(float2*)&pbuf[rid * 8 + wn * 2] = pr;
      }
  }
  __syncthreads();
  if (tid < 128) {
    float s = 0.f, q = 0.f;
#pragma unroll
    for (int w = 0; w < 4; ++w) {
      float2 pr = *(float2*)&pbuf[tid * 8 + w * 2];
      s += pr.x; q += pr.y;
    }
    const float mu  = s * (1.0f / C_);
    const float var = q * (1.0f / C_) - mu * mu;
    float2 mr = {mu, rsqrtf(var + 1e-6f)};
    *(float2*)&rbm[tid * 2] = mr;
  }
  __syncthreads();
  // ---- epilogue phase 2: normalize + write Y ----
  float wc[6], bc[6];
#pragma unroll
  for (int jn = 0; jn < 6; ++jn) {
    const int col = wn * 96 + jn * 16 + ll;
    wc[jn] = w2[col]; bc[jn] = b2[col];
  }
#pragma unroll
  for (int im = 0; im < 4; ++im) {
    const int rid = wm * 64 + im * 16 + quad * 4;
#pragma unroll
    for (int r = 0; r < 4; ++r) {
      float2 mr = *(float2*)&rbm[(rid + r) * 2];
#pragma unroll
      for (int jn = 0; jn < 6; ++jn) {
        const int col = wn * 96 + jn * 16 + ll;
        Y[(size_t)(m0 + rid + r) * C_ + col] =
            f2b((acc[im][jn][r] - mr.x) * mr.y * wc[jn] + bc[jn]);
      }
    }
  }
}

// ---------------- MFMA flash attention (R19: K-clamp removed) ----------------
// Overflow K prefetch rows (784..831, only at t=11) land in the adjacent VB
// region (valid memory); the garbage S[1..3] at t=12 is provably unused
// (tail path computes exp2 only on S[0] = keys 768..783, genuine rows).
#define QS_STR 72
__global__ __launch_bounds__(512) void attn_mfma(
    const u16* __restrict__ Q, const u16* __restrict__ Kb,
    const u16* __restrict__ Vb, u16* __restrict__ O) {
  __shared__ u16 Ks[2][64 * 64];        // 16 KB  (swizzled, stride 64)
  __shared__ u16 Vt[2][48 * QS_STR];    // 13.5 KB (transposed, permuted cols)
  const int tid  = threadIdx.x;
  const int wave = tid >> 6;
  const int lane = tid & 63;
  const int quad = lane >> 4;
  const int ll   = lane & 15;
  // XCD swizzle: xcd = blk&7 owns orig in [xcd*200, xcd*200+200).
  const int blk  = blockIdx.x;
  const int orig = (blk & 7) * 200 + (blk >> 3);
  const int bh   = orig / 25;
  const int qt   = orig - bh * 25;
  const int b    = bh >> 3, h = bh & 7;
  const int q0   = qt * 128;

  // ---- Q fragments in registers (B-operand of swapped QK); pre-scaled
  // by d^-0.5 * log2e in the Q projection. Cols 48..63 zero-padded.
  bf16x8 qf0, qf1;
  {
    int qrow = q0 + wave * 16 + ll;
    if (qrow >= N_TOK) qrow = N_TOK - 1;       // rows masked at output
    const u16* qp = Q + ((size_t)(b * N_TOK) + qrow) * C_ + h * DH;
    qf0 = *(const bf16x8*)(qp + quad * 8);                    // c = quad*8..+8
    if (quad < 2) qf1 = *(const bf16x8*)(qp + 32 + quad * 8); // c = 32..48
    else          qf1 = (bf16x8){0, 0, 0, 0, 0, 0, 0, 0};     // c = 48..64 pad
  }

  // K tile prefetch: pre-swizzled global source, linear LDS dest (m173).
  const int krow = (wave << 3) + (lane >> 3);          // tile row 0..63
  const int kgrp = (lane & 7) ^ (lane >> 3);           // group g = slot ^ (row&7)
  const size_t kbase_g = (size_t)(b * NK) * C_ + h * DH + kgrp * 8;

  // V staging: column permutation pcol = sigma^{-1}:
  // key = nt*16 + qp*4 + r  ->  (nt>>1)*32 + qp*8 + (nt&1)*4 + r
  uint4 vreg;
  const int vkey  = lane;
  const int vcol  = ((vkey >> 5) << 5) + (((vkey & 15) >> 2) << 3) +
                    (((vkey >> 4) & 1) << 2) + (vkey & 3);

  // ---- prologue: stage tile 0 ----
  {
    gload_lds16(Kb + kbase_g + (size_t)krow * C_, &Ks[0][wave << 9]);
    if (wave < 6) {
      vreg = *(const uint4*)(Vb + ((size_t)(b * NK) + vkey) * C_ + h * DH + wave * 8);
      const u16* vp = (const u16*)&vreg;
#pragma unroll
      for (int j = 0; j < 8; ++j)
        Vt[0][(wave * 8 + j) * QS_STR + vcol] = vp[j];
    }
  }
  __syncthreads();

  f32x4 Ofr[3] = {{0.f,0.f,0.f,0.f},{0.f,0.f,0.f,0.f},{0.f,0.f,0.f,0.f}};
  f32x4 Sden = {0.f, 0.f, 0.f, 0.f};
  const short oneb = (short)0x3F80;   // bf16 1.0
  const bf16x8 ones = {oneb, oneb, oneb, oneb, oneb, oneb, oneb, oneb};

  for (int t = 0; t < 13; ++t) {
    const int cur = t & 1, nxt = cur ^ 1;

    // -- issue next-tile loads first; latency hides under QK+softmax+PV --
    if (t < 12) {
      const int knext = (t + 1) * 64;
      gload_lds16(Kb + kbase_g + (size_t)(knext + krow) * C_, &Ks[nxt][wave << 9]);
      if (wave < 6) {
        int vk = knext + vkey; if (vk >= NK) vk = NK - 1;   // keep: P=0*NaN hazard
        vreg = *(const uint4*)(Vb + ((size_t)(b * NK) + vk) * C_ + h * DH + wave * 8);
      }
    }

    // -- swapped QK^T: S^T[key][qrow], A = K fragments from LDS, B = Q regs --
    f32x4 S[4];
    __builtin_amdgcn_s_setprio(1);
#pragma unroll
    for (int nt = 0; nt < 4; ++nt) {
      const int rb = (nt * 16 + ll) * 64;
      bf16x8 k0f = *(const bf16x8*)&Ks[cur][rb + ((quad    ) ^ (ll & 7)) * 8];
      bf16x8 k1f = *(const bf16x8*)&Ks[cur][rb + ((quad + 4) ^ (ll & 7)) * 8];
      f32x4 acc = {0.f, 0.f, 0.f, 0.f};
      acc = __builtin_amdgcn_mfma_f32_16x16x32_bf16(k0f, qf0, acc, 0, 0, 0);
      acc = __builtin_amdgcn_mfma_f32_16x16x32_bf16(k1f, qf1, acc, 0, 0, 0);
      S[nt] = acc;
    }
    __builtin_amdgcn_s_setprio(0);

    // -- exp2 + RNE pack into PV A-frags. Keys per lane ARE the fragment.
    // Tiles 0..11 fully valid; tile 12 (keys 768..831): valid iff nt==0.
    unsigned pw[8];
    if (t != 12) {
#pragma unroll
      for (int nt = 0; nt < 4; ++nt)
#pragma unroll
        for (int rr = 0; rr < 2; ++rr)
          pw[nt * 2 + rr] =
              cvtpk_bf16(exp2_fast(S[nt][rr * 2]), exp2_fast(S[nt][rr * 2 + 1]));
    } else {
#pragma unroll
      for (int rr = 0; rr < 2; ++rr)
        pw[rr] = cvtpk_bf16(exp2_fast(S[0][rr * 2]), exp2_fast(S[0][rr * 2 + 1]));
#pragma unroll
      for (int i = 2; i < 8; ++i) pw[i] = 0u;
    }
    union PU { unsigned w[4]; bf16x8 v; };
    PU pk0, pk1;
#pragma unroll
    for (int i = 0; i < 4; ++i) { pk0.w[i] = pw[i]; pk1.w[i] = pw[4 + i]; }

    __builtin_amdgcn_s_setprio(1);
    // -- denominator: row sums via ones-MFMA (matrix pipe, not VALU) --
    Sden = __builtin_amdgcn_mfma_f32_16x16x32_bf16(pk0.v, ones, Sden, 0, 0, 0);
    Sden = __builtin_amdgcn_mfma_f32_16x16x32_bf16(pk1.v, ones, Sden, 0, 0, 0);

    // -- PV: B = V fragments from permuted-column Vt --
#pragma unroll
    for (int dt = 0; dt < 3; ++dt) {
      bf16x8 v0 = *(const bf16x8*)&Vt[cur][(dt * 16 + ll) * QS_STR + quad * 8];
      bf16x8 v1 = *(const bf16x8*)&Vt[cur][(dt * 16 + ll) * QS_STR + 32 + quad * 8];
      Ofr[dt] = __builtin_amdgcn_mfma_f32_16x16x32_bf16(pk0.v, v0, Ofr[dt], 0, 0, 0);
      Ofr[dt] = __builtin_amdgcn_mfma_f32_16x16x32_bf16(pk1.v, v1, Ofr[dt], 0, 0, 0);
    }
    __builtin_amdgcn_s_setprio(0);

    // -- land V regs into Vt[nxt] (auto vmcnt wait on vreg use) --
    if (t < 12 && wave < 6) {
      const u16* vp = (const u16*)&vreg;
#pragma unroll
      for (int j = 0; j < 8; ++j)
        Vt[nxt][(wave * 8 + j) * QS_STR + vcol] = vp[j];
    }
    // One barrier/iter: its vmcnt(0)+lgkmcnt(0) drain also retires the
    // K global_load_lds (in flight during the whole compute phase).
    __syncthreads();
  }

  // Sden[r] = denominator for qrow quad*4+r (same value in every ll lane).
  float inv[4];
#pragma unroll
  for (int r = 0; r < 4; ++r) inv[r] = 1.0f / Sden[r];
#pragma unroll
  for (int dt = 0; dt < 3; ++dt)
#pragma unroll
    for (int r = 0; r < 4; ++r) {
      int qrow = q0 + wave * 16 + quad * 4 + r;
      if (qrow < N_TOK)
        O[((size_t)b * N_TOK + qrow) * C_ + h * DH + dt * 16 + ll] =
            f2b(Ofr[dt][r] * inv[r]);
    }
}

// ---------------- Diagnostics ----------------
__global__ __launch_bounds__(256) void marker_fill(
    float* __restrict__ out, size_t n, float val) {
  size_t i = (size_t)blockIdx.x * 256 + threadIdx.x;
  const size_t stride = (size_t)gridDim.x * 256;
  for (; i < n; i += stride) out[i] = 0.f;
  if (blockIdx.x == 0 && threadIdx.x == 0) out[0] = val;
}

// ---------------- launch ----------------
extern "C" void kernel_launch(void* const* d_in, const int* in_sizes, int n_in,
                              void* d_out, int out_size, void* d_ws, size_t ws_size,
                              hipStream_t stream) {
  const float* x    = (const float*)d_in[0];
  const float* ln1w = (const float*)d_in[1];
  const float* ln1b = (const float*)d_in[2];
  const float* qw   = (const float*)d_in[3];
  const float* qb   = (const float*)d_in[4];
  const float* kw   = (const float*)d_in[5];
  const float* kb   = (const float*)d_in[6];
  const float* vw   = (const float*)d_in[7];
  const float* vb   = (const float*)d_in[8];
  const float* pw   = (const float*)d_in[9];
  const float* pb   = (const float*)d_in[10];
  const float* ln2w = (const float*)d_in[11];
  const float* ln2b = (const float*)d_in[12];
  const float* fc1w = (const float*)d_in[13];
  const float* fc1b = (const float*)d_in[14];
  const float* fc2w = (const float*)d_in[15];
  const float* fc2b = (const float*)d_in[16];

  const size_t BUF = (size_t)M1 * C_;
  float* outf = (float*)d_out;

  {
    static const int exp_sizes[19] = {
      M1 * C_, C_, C_, C_ * C_, C_, C_ * C_, C_, C_ * C_, C_, C_ * C_, C_,
      C_, C_, C_ * HID, HID, HID * C_, C_, 1, 1};
    int bad = -1;
    if (n_in != 19) bad = 99;
    else {
      for (int i = 0; i < 19; ++i)
        if (in_sizes[i] != exp_sizes[i]) { bad = i; break; }
    }
    if (bad >= 0) {
      marker_fill<<<1024, 256, 0, stream>>>(outf, BUF, 10000.0f + (float)bad);
      return;
    }
  }
  const size_t need_min  = 4096 + 3 * BUF * sizeof(u16);                     // 57.8 MB
  const size_t need_full = 4096 + (3 * BUF + (size_t)M1 * HID) * sizeof(u16); // 96.4 MB
  if (ws_size < need_min) {
    marker_fill<<<1024, 256, 0, stream>>>(outf, BUF, 30000.0f + (float)(ws_size >> 20));
    return;
  }
  const bool full_mlp = (ws_size >= need_full);

  u16* T0 = (u16*)((char*)d_ws + 4096);
  u16* T1 = T0 + BUF;
  u16* U  = T1 + BUF;
  u16* P  = U;
  u16* KB = U + (size_t)M2 * C_;
  u16* VB = U + (size_t)2 * M2 * C_;
  u16* HBq = U;                              // quarter-HB fallback overlay
  u16* HBfull = U + BUF;                     // full-M HB (only if full_mlp)
  u16* WTb = U + BUF - (size_t)(4 * C_ * C_ + 2 * C_ * HID);
  u16* wtq = WTb;
  u16* wtk = wtq + C_ * C_;
  u16* wtv = wtk + C_ * C_;
  u16* wtp = wtv + C_ * C_;
  u16* wtf1 = wtp + C_ * C_;
  u16* wtf2 = wtf1 + (size_t)C_ * HID;

  // 0+1. Fused LN1 + pool + all six weight transposes (one launch).
  {
    TransArgs ta;
    ta.src[0] = qw;   ta.dst[0] = wtq;  ta.K[0] = C_;  ta.N[0] = C_;
    ta.src[1] = kw;   ta.dst[1] = wtk;  ta.K[1] = C_;  ta.N[1] = C_;
    ta.src[2] = vw;   ta.dst[2] = wtv;  ta.K[2] = C_;  ta.N[2] = C_;
    ta.src[3] = pw;   ta.dst[3] = wtp;  ta.K[3] = C_;  ta.N[3] = C_;
    ta.src[4] = fc1w; ta.dst[4] = wtf1; ta.K[4] = C_;  ta.N[4] = HID;
    ta.src[5] = fc2w; ta.dst[5] = wtf2; ta.K[5] = HID; ta.N[5] = C_;
    ln1_pool_tr<<<TRB0 + 288, 256, 0, stream>>>(x, ln1w, ln1b, T0, P, ta);
  }

  // 2. Q/K/V projections, exact-work XCD-swizzled grid (882 blocks).
  {
    QKVArgs qa;
    qa.A[0] = T0; qa.BT[0] = wtq; qa.bias[0] = qb; qa.C[0] = T1;
    qa.A[1] = P;  qa.BT[1] = wtk; qa.bias[1] = kb; qa.C[1] = KB;
    qa.A[2] = P;  qa.BT[2] = wtv; qa.bias[2] = vb; qa.C[2] = VB;
    qa.osc[0] = 0.20823509507f;  // d^-0.5 * log2(e)
    qa.osc[1] = 1.0f;
    qa.osc[2] = 1.0f;
    gemm_qkv<<<dim3(882), 256, 0, stream>>>(qa);
  }

  // 3. MFMA flash attention -> T0  (1600 blocks, XCD-swizzled 1-D grid)
  attn_mfma<<<dim3(1600), 512, 0, stream>>>(T1, KB, VB, T0);

  // 4+5 fused. x1 = x + T0 @ pw + pb -> T1; LN2(x1) -> T0.
  proj_res_ln2<<<dim3(196), 512, 0, stream>>>(
      T0, wtp, pb, x, ln2w, ln2b, T1, T0);

  // 6/7. MLP (1-D XCD-swizzled grids; 128x128 tiles — wide fc1 regressed
  // in R20 due to 392-block/2-per-CU dispatch tail, reverted).
  if (full_mlp) {
    gemm_bt<1, false, false><<<dim3(1176), 256, 0, stream>>>(
        T0, wtf1, fc1b, nullptr, HBfull, HID, C_, 6);
    gemm_bt<2, false, true><<<dim3(588), 256, 0, stream>>>(
        HBfull, wtf2, fc2b, T1, outf, C_, HID, 3);
  } else {
    for (int qtr = 0; qtr < 4; ++qtr) {
      const size_t ro = (size_t)qtr * M1Q;
      gemm_bt<1, false, false><<<dim3(294), 256, 0, stream>>>(
          T0 + ro * C_, wtf1, fc1b, nullptr, HBq, HID, C_, 6);
      gemm_bt<2, false, true><<<dim3(147), 256, 0, stream>>>(
          HBq, wtf2, fc2b, T1 + ro * C_, outf + ro * C_, C_, HID, 3);
    }
  }
}

// Round 19
// 304.026 us; speedup vs baseline: 1.0494x; 1.0050x over previous
//
#include <hip/hip_runtime.h>
#include <math.h>

#define B_    8
#define N_TOK 3136
#define C_    384
#define DH    48
#define NK    784
#define HID   768
#define M1    25088
#define M2    6272
#define M1Q   6272      // quarter of M1

typedef unsigned short u16;
typedef __attribute__((ext_vector_type(8))) short bf16x8;
typedef __attribute__((ext_vector_type(4))) float f32x4;

__device__ __forceinline__ float b2f(u16 u) {
  return __uint_as_float(((unsigned)u) << 16);
}
__device__ __forceinline__ u16 f2b(float f) {
  unsigned u = __float_as_uint(f);
  return (u16)((u + 0x7fffu + ((u >> 16) & 1u)) >> 16);  // RNE
}
__device__ __forceinline__ void gload_lds16(const u16* g, u16* l) {
  __builtin_amdgcn_global_load_lds(
      (const __attribute__((address_space(1))) void*)g,
      (__attribute__((address_space(3))) void*)l, 16, 0, 0);
}
// RNE pack of two f32 into one dword of 2x bf16 (low=a, high=b). gfx950 has
// no builtin for v_cvt_pk_bf16_f32 (guide T12) -- inline asm, pure VALU op.
__device__ __forceinline__ unsigned cvtpk_bf16(float a, float b) {
  unsigned r;
  asm("v_cvt_pk_bf16_f32 %0, %1, %2" : "=v"(r) : "v"(a), "v"(b));
  return r;
}
// 2^x via the native trans op (input pre-scaled by log2e upstream).
__device__ __forceinline__ float exp2_fast(float x) {
  float r;
  asm("v_exp_f32 %0, %1" : "=v"(r) : "v"(x));
  return r;
}
// Bijective XCD-contiguous block remap (m204): hardware assigns block i to
// XCD i%8; this gives each XCD a CONTIGUOUS range of logical work ids, so
// blocks sharing an A panel land on the same XCD's L2.
__device__ __forceinline__ int xcd_swz(int blk, int nwg) {
  const int q = nwg >> 3, r = nwg & 7;
  const int x = blk & 7, j = blk >> 3;
  return (x < r ? x * (q + 1) : r * (q + 1) + (x - r) * q) + j;
}

// -------- Batched weight transpose args (merged into ln1_pool_tr) --------
struct TransArgs {
  const float* src[6];
  u16* dst[6];
  int K[6], N[6];
};

// --- Fused LN1 + pool + weight transposes (all independent; one launch) ---
// blocks [0, 6272): LayerNorm, 4 rows each (float2-vectorized).
// blocks [6272, 10976): 2x2 avg pool, 2 cols/thread.
// blocks [10976, 11264): 6 weight transpose+converts (64x64 tiles).
#define LN1B  (M1 / 4)                   // 6272
#define POOLB ((M2 * (C_ / 2)) / 256)    // 4704
#define TRB0  (LN1B + POOLB)             // 10976
__global__ __launch_bounds__(256) void ln1_pool_tr(
    const float* __restrict__ X, const float* __restrict__ w,
    const float* __restrict__ b, u16* __restrict__ Y, u16* __restrict__ KV,
    TransArgs ta) {
  __shared__ u16 tile[64][73];
  const int blk = blockIdx.x;
  if (blk < LN1B) {
    const int row = blk * 4 + (threadIdx.x >> 6);
    const int lane = threadIdx.x & 63;
    const float2* xp = (const float2*)(X + (size_t)row * C_);
    float2 vv[3];
#pragma unroll
    for (int i = 0; i < 3; ++i) vv[i] = xp[lane + 64 * i];
    float s = 0.f;
#pragma unroll
    for (int i = 0; i < 3; ++i) s += vv[i].x + vv[i].y;
#pragma unroll
    for (int off = 32; off > 0; off >>= 1) s += __shfl_xor(s, off);
    const float mu = s * (1.0f / C_);
    float q = 0.f;
#pragma unroll
    for (int i = 0; i < 3; ++i) {
      float dx = vv[i].x - mu, dy = vv[i].y - mu;
      q += dx * dx + dy * dy;
    }
#pragma unroll
    for (int off = 32; off > 0; off >>= 1) q += __shfl_xor(q, off);
    const float r = rsqrtf(q * (1.0f / C_) + 1e-6f);
    const float2* wp = (const float2*)w;
    const float2* bp = (const float2*)b;
#pragma unroll
    for (int i = 0; i < 3; ++i) {
      int cp = lane + 64 * i;
      float2 wv = wp[cp], bv = bp[cp];
      u16 o0 = f2b((vv[i].x - mu) * r * wv.x + bv.x);
      u16 o1 = f2b((vv[i].y - mu) * r * wv.y + bv.y);
      ushort2 o = {o0, o1};
      *(ushort2*)&Y[(size_t)row * C_ + cp * 2] = o;
    }
  } else if (blk < TRB0) {
    int t = (blk - LN1B) * 256 + threadIdx.x;  // pair index
    if (t >= M2 * (C_ / 2)) return;
    int cp = t % (C_ / 2);
    int row = t / (C_ / 2);
    int bb = row / NK;
    int rr = row - bb * NK;
    int hk = rr / 28;
    int wk = rr - hk * 28;
    const float* p = X + ((size_t)(bb * N_TOK + hk * 112 + wk * 2)) * C_ + cp * 2;
    float2 a0 = *(const float2*)(p);
    float2 a1 = *(const float2*)(p + C_);
    float2 a2 = *(const float2*)(p + 56 * C_);
    float2 a3 = *(const float2*)(p + 57 * C_);
    ushort2 o = {f2b(0.25f * (a0.x + a1.x + a2.x + a3.x)),
                 f2b(0.25f * (a0.y + a1.y + a2.y + a3.y))};
    *(ushort2*)&KV[(size_t)t * 2] = o;
  } else {
    // transpose blocks: id0..3 (384x384): 36 each; id4 (384x768): 72;
    // id5 (768x384): 72.
    const int tr = blk - TRB0;
    int id, bx, by;
    if (tr < 144)      { id = tr / 36; int rm = tr % 36; bx = rm % 6;  by = rm / 6; }
    else if (tr < 216) { id = 4;       int rm = tr - 144; bx = rm % 12; by = rm / 12; }
    else               { id = 5;       int rm = tr - 216; bx = rm % 6;  by = rm / 6; }
    const float* W = ta.src[id];
    u16* WT = ta.dst[id];
    const int K = ta.K[id], N = ta.N[id];
    const int k0 = by * 64, n0 = bx * 64;
    for (int i = threadIdx.x; i < 64 * 64; i += 256) {
      int kk = i >> 6, nn = i & 63;
      tile[kk][nn] = f2b(W[(size_t)(k0 + kk) * N + n0 + nn]);
    }
    __syncthreads();
    for (int i = threadIdx.x; i < 64 * 64; i += 256) {
      int nn = i >> 6, kk = i & 63;
      WT[(size_t)(n0 + nn) * K + k0 + kk] = tile[kk][nn];
    }
  }
}

// ---------------- MFMA GEMM core: C(m0..+128, n0..+128) ----------------
// oscale multiplies (acc + bias) before EPI transforms (used to fold the
// attention softmax scale * log2(e) into the Q projection; 1.0f elsewhere).
template<int EPI, bool RES32, bool OUT32>
__device__ __forceinline__ void gemm_core(
    const u16* __restrict__ A, const u16* __restrict__ BT,
    const float* __restrict__ bias, const void* __restrict__ resv,
    void* __restrict__ Cv, int N, int K, float oscale, int m0, int n0) {
  __shared__ u16 As[128 * 64];
  __shared__ u16 Bs[128 * 64];
  const int tid  = threadIdx.x;
  const int wave = tid >> 6;
  const int lane = tid & 63;
  const int quad = lane >> 4;
  const int ll   = lane & 15;
  const int wm   = wave >> 1, wn = wave & 1;

  const int srow = wave * 32 + (lane >> 3);
  const int sgs  = lane & 7;

  f32x4 acc[4][4];
#pragma unroll
  for (int i = 0; i < 4; ++i)
#pragma unroll
    for (int j = 0; j < 4; ++j) acc[i][j] = (f32x4){0.f, 0.f, 0.f, 0.f};

  for (int kk0 = 0; kk0 < K; kk0 += 64) {
    __syncthreads();
#pragma unroll
    for (int c = 0; c < 4; ++c) {
      const int r = srow + c * 8;
      const int g = sgs ^ (r & 7);
      gload_lds16(A  + (size_t)(m0 + r) * K + kk0 + g * 8,
                  As + (size_t)(wave * 32 + c * 8) * 64);
      gload_lds16(BT + (size_t)(n0 + r) * K + kk0 + g * 8,
                  Bs + (size_t)(wave * 32 + c * 8) * 64);
    }
    __syncthreads();
#pragma unroll
    for (int ks = 0; ks < 2; ++ks) {
      const int gsw = (quad + 4 * ks) ^ (ll & 7);
      bf16x8 af[4], bfr[4];
#pragma unroll
      for (int im = 0; im < 4; ++im)
        af[im] = *(const bf16x8*)&As[(size_t)(wm * 64 + im * 16 + ll) * 64 + gsw * 8];
#pragma unroll
      for (int jn = 0; jn < 4; ++jn)
        bfr[jn] = *(const bf16x8*)&Bs[(size_t)(wn * 64 + jn * 16 + ll) * 64 + gsw * 8];
#pragma unroll
      for (int im = 0; im < 4; ++im)
#pragma unroll
        for (int jn = 0; jn < 4; ++jn)
          acc[im][jn] = __builtin_amdgcn_mfma_f32_16x16x32_bf16(
              af[im], bfr[jn], acc[im][jn], 0, 0, 0);
    }
  }

  float bb[4];
#pragma unroll
  for (int jn = 0; jn < 4; ++jn) bb[jn] = bias[n0 + wn * 64 + jn * 16 + ll];
#pragma unroll
  for (int im = 0; im < 4; ++im) {
    const int row = m0 + wm * 64 + im * 16 + quad * 4;
#pragma unroll
    for (int jn = 0; jn < 4; ++jn) {
      const int col = n0 + wn * 64 + jn * 16 + ll;
#pragma unroll
      for (int r = 0; r < 4; ++r) {
        float o = (acc[im][jn][r] + bb[jn]) * oscale;
        if (EPI == 1) {
          o = 0.5f * o * (1.0f + erff(o * 0.70710678118654752f));
        } else if (EPI == 2) {
          size_t ri = (size_t)(row + r) * N + col;
          o += RES32 ? ((const float*)resv)[ri] : b2f(((const u16*)resv)[ri]);
        }
        if (OUT32) ((float*)Cv)[(size_t)(row + r) * N + col] = o;
        else       ((u16*)Cv)[(size_t)(row + r) * N + col] = f2b(o);
      }
    }
  }
}

// 1-D grid + bijective XCD swizzle; NX = N-tiles (x fastest -> A-panel
// sharers get consecutive logical ids -> same XCD).
template<int EPI, bool RES32, bool OUT32>
__global__ __launch_bounds__(256) void gemm_bt(
    const u16* __restrict__ A, const u16* __restrict__ BT,
    const float* __restrict__ bias, const void* __restrict__ resv,
    void* __restrict__ Cv, int N, int K, int NX) {
  const int flat = xcd_swz(blockIdx.x, gridDim.x);
  const int y = flat / NX, x = flat - y * NX;
  gemm_core<EPI, RES32, OUT32>(A, BT, bias, resv, Cv, N, K, 1.0f,
                               y << 7, x << 7);
}

// ---- BM=64 GEMM variant (R22): 64x128 tile, 4 waves (2x2), 24 KB LDS ----
// For fc2 (K=768, was 588 blocks = 2.3/CU -> latency-exposed barrier
// drains). 64-row tiles double the grid to 1176 (4.6/CU, ~6 blocks/CU by
// LDS) so resident-block overlap hides the 12 K-iteration drains.
template<int EPI, bool RES32, bool OUT32>
__global__ __launch_bounds__(256) void gemm_bt64(
    const u16* __restrict__ A, const u16* __restrict__ BT,
    const float* __restrict__ bias, const void* __restrict__ resv,
    void* __restrict__ Cv, int N, int K, int NX) {
  const int flat = xcd_swz(blockIdx.x, gridDim.x);
  const int y = flat / NX, x = flat - y * NX;
  const int m0 = y << 6, n0 = x << 7;
  __shared__ u16 As[64 * 64];    // 8 KB
  __shared__ u16 Bs[128 * 64];   // 16 KB
  const int tid  = threadIdx.x;
  const int wave = tid >> 6;
  const int lane = tid & 63;
  const int quad = lane >> 4;
  const int ll   = lane & 15;
  const int wm   = wave >> 1, wn = wave & 1;   // 2x2 waves: 32 rows x 64 cols

  const int srow8 = lane >> 3;   // 0..7 row within an 8-row stripe
  const int sgs   = lane & 7;

  f32x4 acc[2][4];
#pragma unroll
  for (int i = 0; i < 2; ++i)
#pragma unroll
    for (int j = 0; j < 4; ++j) acc[i][j] = (f32x4){0.f, 0.f, 0.f, 0.f};

  for (int kk0 = 0; kk0 < K; kk0 += 64) {
    __syncthreads();
    // A: 64 rows, 8 rows per wave-instruction; wave covers rows wave*16+c*8.
#pragma unroll
    for (int c = 0; c < 2; ++c) {
      const int r = wave * 16 + c * 8 + srow8;
      const int g = sgs ^ (r & 7);
      gload_lds16(A + (size_t)(m0 + r) * K + kk0 + g * 8,
                  As + (size_t)(wave * 16 + c * 8) * 64);
    }
    // B: 128 rows; wave covers rows wave*32+c*8.
#pragma unroll
    for (int c = 0; c < 4; ++c) {
      const int r = wave * 32 + c * 8 + srow8;
      const int g = sgs ^ (r & 7);
      gload_lds16(BT + (size_t)(n0 + r) * K + kk0 + g * 8,
                  Bs + (size_t)(wave * 32 + c * 8) * 64);
    }
    __syncthreads();
#pragma unroll
    for (int ks = 0; ks < 2; ++ks) {
      const int gsw = (quad + 4 * ks) ^ (ll & 7);
      bf16x8 af[2], bfr[4];
#pragma unroll
      for (int im = 0; im < 2; ++im)
        af[im] = *(const bf16x8*)&As[(size_t)(wm * 32 + im * 16 + ll) * 64 + gsw * 8];
#pragma unroll
      for (int jn = 0; jn < 4; ++jn)
        bfr[jn] = *(const bf16x8*)&Bs[(size_t)(wn * 64 + jn * 16 + ll) * 64 + gsw * 8];
#pragma unroll
      for (int im = 0; im < 2; ++im)
#pragma unroll
        for (int jn = 0; jn < 4; ++jn)
          acc[im][jn] = __builtin_amdgcn_mfma_f32_16x16x32_bf16(
              af[im], bfr[jn], acc[im][jn], 0, 0, 0);
    }
  }

  float bb[4];
#pragma unroll
  for (int jn = 0; jn < 4; ++jn) bb[jn] = bias[n0 + wn * 64 + jn * 16 + ll];
#pragma unroll
  for (int im = 0; im < 2; ++im) {
    const int row = m0 + wm * 32 + im * 16 + quad * 4;
#pragma unroll
    for (int jn = 0; jn < 4; ++jn) {
      const int col = n0 + wn * 64 + jn * 16 + ll;
#pragma unroll
      for (int r = 0; r < 4; ++r) {
        float o = acc[im][jn][r] + bb[jn];
        if (EPI == 1) {
          o = 0.5f * o * (1.0f + erff(o * 0.70710678118654752f));
        } else if (EPI == 2) {
          size_t ri = (size_t)(row + r) * N + col;
          o += RES32 ? ((const float*)resv)[ri] : b2f(((const u16*)resv)[ri]);
        }
        if (OUT32) ((float*)Cv)[(size_t)(row + r) * N + col] = o;
        else       ((u16*)Cv)[(size_t)(row + r) * N + col] = f2b(o);
      }
    }
  }
}

// Q/K/V fused, exact-work 1-D grid (882 = Q:588 + KV:294 interleaved),
// XCD-swizzled. K and V blocks sharing an A(P)-panel are adjacent ids.
struct QKVArgs {
  const u16* A[3];
  const u16* BT[3];
  const float* bias[3];
  u16* C[3];
  float osc[3];
};
__global__ __launch_bounds__(256) void gemm_qkv(QKVArgs a) {
  const int flat = xcd_swz(blockIdx.x, gridDim.x);
  int z, y, x;
  if (flat < 588) {
    z = 0; y = flat / 3; x = flat - y * 3;
  } else {
    int p = flat - 588;              // 0..293: 49 panels x {K,V} x 3 cols
    y = p / 6;
    int t2 = p - y * 6;
    z = (t2 >= 3) ? 2 : 1;
    x = (t2 >= 3) ? t2 - 3 : t2;
  }
  gemm_core<0, false, false>(a.A[z], a.BT[z], a.bias[z], nullptr, a.C[z],
                             C_, C_, a.osc[z], y << 7, x << 7);
}

// ------- Fused proj + residual + LN2 (R17): BM=128, BN=384 (full width) -----
// One block owns 128 full rows: x1 = x + attnO @ pw + pb -> T1 (bf16), then
// LN2(x1) -> T0 in the same kernel (row stats via one LDS partial exchange).
// No XCD swizzle: BN = full width -> each A panel read by exactly one block.
// Grid 196 <= 256 CUs -> single dispatch wave (why wide works HERE only).
__global__ __launch_bounds__(512) void proj_res_ln2(
    const u16* A, const u16* __restrict__ BT,
    const float* __restrict__ bias, const float* __restrict__ xres,
    const float* __restrict__ w2, const float* __restrict__ b2,
    u16* __restrict__ X1, u16* Y) {
  __shared__ u16 As[128 * 64];   // 16 KB (reused as f32 partial buf in epilogue)
  __shared__ u16 Bs[384 * 64];   // 48 KB
  const int tid  = threadIdx.x;
  const int wave = tid >> 6;
  const int lane = tid & 63;
  const int quad = lane >> 4;
  const int ll   = lane & 15;
  const int wm   = wave >> 2;        // 0..1  (64 rows each)
  const int wn   = wave & 3;         // 0..3  (96 cols each)
  const int m0   = blockIdx.x << 7;

  const int srow = tid >> 3;                 // 0..63 within each 64-row chunk
  const int g    = (lane & 7) ^ (lane >> 3); // XOR-swizzled source group

  f32x4 acc[4][6];
#pragma unroll
  for (int i = 0; i < 4; ++i)
#pragma unroll
    for (int j = 0; j < 6; ++j) acc[i][j] = (f32x4){0.f, 0.f, 0.f, 0.f};

  for (int kk0 = 0; kk0 < 384; kk0 += 64) {
    __syncthreads();
    // stage 512 combined rows (A:0..127, B:0..383), 64 rows per chunk i
#pragma unroll
    for (int i = 0; i < 8; ++i) {
      const int row = i * 64 + srow;
      if (i < 2) {
        gload_lds16(A + (size_t)(m0 + row) * 384 + kk0 + g * 8,
                    As + (size_t)(i * 64 + wave * 8) * 64);
      } else {
        gload_lds16(BT + (size_t)(row - 128) * 384 + kk0 + g * 8,
                    Bs + (size_t)((i - 2) * 64 + wave * 8) * 64);
      }
    }
    __syncthreads();
#pragma unroll
    for (int ks = 0; ks < 2; ++ks) {
      const int gsw = (quad + 4 * ks) ^ (ll & 7);
      bf16x8 af[4], bfr[6];
#pragma unroll
      for (int im = 0; im < 4; ++im)
        af[im] = *(const bf16x8*)&As[(size_t)(wm * 64 + im * 16 + ll) * 64 + gsw * 8];
#pragma unroll
      for (int jn = 0; jn < 6; ++jn)
        bfr[jn] = *(const bf16x8*)&Bs[(size_t)(wn * 96 + jn * 16 + ll) * 64 + gsw * 8];
#pragma unroll
      for (int im = 0; im < 4; ++im)
#pragma unroll
        for (int jn = 0; jn < 6; ++jn)
          acc[im][jn] = __builtin_amdgcn_mfma_f32_16x16x32_bf16(
              af[im], bfr[jn], acc[im][jn], 0, 0, 0);
    }
  }

  // ---- epilogue phase 1: o = acc + bias + x residual; write X1; keep o ----
  float bb[6];
#pragma unroll
  for (int jn = 0; jn < 6; ++jn) bb[jn] = bias[wn * 96 + jn * 16 + ll];
  float ps[4][4], pq[4][4];
#pragma unroll
  for (int im = 0; im < 4; ++im)
#pragma unroll
    for (int r = 0; r < 4; ++r) { ps[im][r] = 0.f; pq[im][r] = 0.f; }
#pragma unroll
  for (int im = 0; im < 4; ++im) {
    const int rid = wm * 64 + im * 16 + quad * 4;
#pragma unroll
    for (int jn = 0; jn < 6; ++jn) {
      const int col = wn * 96 + jn * 16 + ll;
#pragma unroll
      for (int r = 0; r < 4; ++r) {
        float o = acc[im][jn][r] + bb[jn] +
                  xres[(size_t)(m0 + rid + r) * C_ + col];
        X1[(size_t)(m0 + rid + r) * C_ + col] = f2b(o);
        acc[im][jn][r] = o;
        ps[im][r] += o;
        pq[im][r] += o * o;
      }
    }
  }
  // reduce partials over the 16 ll lanes (rows are ll-invariant)
#pragma unroll
  for (int msk = 1; msk < 16; msk <<= 1)
#pragma unroll
    for (int im = 0; im < 4; ++im)
#pragma unroll
      for (int r = 0; r < 4; ++r) {
        ps[im][r] += __shfl_xor(ps[im][r], msk);
        pq[im][r] += __shfl_xor(pq[im][r], msk);
      }
  __syncthreads();                 // all LDS reads of K-loop done; reuse As
  float* pbuf = (float*)As;        // [128 rows][4 nwaves][2] = 4 KB
  float* rbm  = pbuf + 128 * 8;    // [128 rows][2] = 1 KB (mu, rinv)
  if (ll == 0) {
#pragma unroll
    for (int im = 0; im < 4; ++im)
#pragma unroll
      for (int r = 0; r < 4; ++r) {
        const int rid = wm * 64 + im * 16 + quad * 4 + r;
        float2 pr = {ps[im][r], pq[im][r]};
        *(float2*)&pbuf[rid * 8 + wn * 2] = pr;
      }
  }
  __syncthreads();
  if (tid < 128) {
    float s = 0.f, q = 0.f;
#pragma unroll
    for (int w = 0; w < 4; ++w) {
      float2 pr = *(float2*)&pbuf[tid * 8 + w * 2];
      s += pr.x; q += pr.y;
    }
    const float mu  = s * (1.0f / C_);
    const float var = q * (1.0f / C_) - mu * mu;
    float2 mr = {mu, rsqrtf(var + 1e-6f)};
    *(float2*)&rbm[tid * 2] = mr;
  }
  __syncthreads();
  // ---- epilogue phase 2: normalize + write Y ----
  float wc[6], bc[6];
#pragma unroll
  for (int jn = 0; jn < 6; ++jn) {
    const int col = wn * 96 + jn * 16 + ll;
    wc[jn] = w2[col]; bc[jn] = b2[col];
  }
#pragma unroll
  for (int im = 0; im < 4; ++im) {
    const int rid = wm * 64 + im * 16 + quad * 4;
#pragma unroll
    for (int r = 0; r < 4; ++r) {
      float2 mr = *(float2*)&rbm[(rid + r) * 2];
#pragma unroll
      for (int jn = 0; jn < 6; ++jn) {
        const int col = wn * 96 + jn * 16 + ll;
        Y[(size_t)(m0 + rid + r) * C_ + col] =
            f2b((acc[im][jn][r] - mr.x) * mr.y * wc[jn] + bc[jn]);
      }
    }
  }
}

// ---------------- MFMA flash attention (R19: K-clamp removed) ----------------
// Overflow K prefetch rows (784..831, only at t=11) land in the adjacent VB
// region (valid memory); the garbage S[1..3] at t=12 is provably unused
// (tail path computes exp2 only on S[0] = keys 768..783, genuine rows).
#define QS_STR 72
__global__ __launch_bounds__(512) void attn_mfma(
    const u16* __restrict__ Q, const u16* __restrict__ Kb,
    const u16* __restrict__ Vb, u16* __restrict__ O) {
  __shared__ u16 Ks[2][64 * 64];        // 16 KB  (swizzled, stride 64)
  __shared__ u16 Vt[2][48 * QS_STR];    // 13.5 KB (transposed, permuted cols)
  const int tid  = threadIdx.x;
  const int wave = tid >> 6;
  const int lane = tid & 63;
  const int quad = lane >> 4;
  const int ll   = lane & 15;
  // XCD swizzle: xcd = blk&7 owns orig in [xcd*200, xcd*200+200).
  const int blk  = blockIdx.x;
  const int orig = (blk & 7) * 200 + (blk >> 3);
  const int bh   = orig / 25;
  const int qt   = orig - bh * 25;
  const int b    = bh >> 3, h = bh & 7;
  const int q0   = qt * 128;

  // ---- Q fragments in registers (B-operand of swapped QK); pre-scaled
  // by d^-0.5 * log2e in the Q projection. Cols 48..63 zero-padded.
  bf16x8 qf0, qf1;
  {
    int qrow = q0 + wave * 16 + ll;
    if (qrow >= N_TOK) qrow = N_TOK - 1;       // rows masked at output
    const u16* qp = Q + ((size_t)(b * N_TOK) + qrow) * C_ + h * DH;
    qf0 = *(const bf16x8*)(qp + quad * 8);                    // c = quad*8..+8
    if (quad < 2) qf1 = *(const bf16x8*)(qp + 32 + quad * 8); // c = 32..48
    else          qf1 = (bf16x8){0, 0, 0, 0, 0, 0, 0, 0};     // c = 48..64 pad
  }

  // K tile prefetch: pre-swizzled global source, linear LDS dest (m173).
  const int krow = (wave << 3) + (lane >> 3);          // tile row 0..63
  const int kgrp = (lane & 7) ^ (lane >> 3);           // group g = slot ^ (row&7)
  const size_t kbase_g = (size_t)(b * NK) * C_ + h * DH + kgrp * 8;

  // V staging: column permutation pcol = sigma^{-1}:
  // key = nt*16 + qp*4 + r  ->  (nt>>1)*32 + qp*8 + (nt&1)*4 + r
  uint4 vreg;
  const int vkey  = lane;
  const int vcol  = ((vkey >> 5) << 5) + (((vkey & 15) >> 2) << 3) +
                    (((vkey >> 4) & 1) << 2) + (vkey & 3);

  // ---- prologue: stage tile 0 ----
  {
    gload_lds16(Kb + kbase_g + (size_t)krow * C_, &Ks[0][wave << 9]);
    if (wave < 6) {
      vreg = *(const uint4*)(Vb + ((size_t)(b * NK) + vkey) * C_ + h * DH + wave * 8);
      const u16* vp = (const u16*)&vreg;
#pragma unroll
      for (int j = 0; j < 8; ++j)
        Vt[0][(wave * 8 + j) * QS_STR + vcol] = vp[j];
    }
  }
  __syncthreads();

  f32x4 Ofr[3] = {{0.f,0.f,0.f,0.f},{0.f,0.f,0.f,0.f},{0.f,0.f,0.f,0.f}};
  f32x4 Sden = {0.f, 0.f, 0.f, 0.f};
  const short oneb = (short)0x3F80;   // bf16 1.0
  const bf16x8 ones = {oneb, oneb, oneb, oneb, oneb, oneb, oneb, oneb};

  for (int t = 0; t < 13; ++t) {
    const int cur = t & 1, nxt = cur ^ 1;

    // -- issue next-tile loads first; latency hides under QK+softmax+PV --
    if (t < 12) {
      const int knext = (t + 1) * 64;
      gload_lds16(Kb + kbase_g + (size_t)(knext + krow) * C_, &Ks[nxt][wave << 9]);
      if (wave < 6) {
        int vk = knext + vkey; if (vk >= NK) vk = NK - 1;   // keep: P=0*NaN hazard
        vreg = *(const uint4*)(Vb + ((size_t)(b * NK) + vk) * C_ + h * DH + wave * 8);
      }
    }

    // -- swapped QK^T: S^T[key][qrow], A = K fragments from LDS, B = Q regs --
    f32x4 S[4];
    __builtin_amdgcn_s_setprio(1);
#pragma unroll
    for (int nt = 0; nt < 4; ++nt) {
      const int rb = (nt * 16 + ll) * 64;
      bf16x8 k0f = *(const bf16x8*)&Ks[cur][rb + ((quad    ) ^ (ll & 7)) * 8];
      bf16x8 k1f = *(const bf16x8*)&Ks[cur][rb + ((quad + 4) ^ (ll & 7)) * 8];
      f32x4 acc = {0.f, 0.f, 0.f, 0.f};
      acc = __builtin_amdgcn_mfma_f32_16x16x32_bf16(k0f, qf0, acc, 0, 0, 0);
      acc = __builtin_amdgcn_mfma_f32_16x16x32_bf16(k1f, qf1, acc, 0, 0, 0);
      S[nt] = acc;
    }
    __builtin_amdgcn_s_setprio(0);

    // -- exp2 + RNE pack into PV A-frags. Keys per lane ARE the fragment.
    // Tiles 0..11 fully valid; tile 12 (keys 768..831): valid iff nt==0.
    unsigned pw[8];
    if (t != 12) {
#pragma unroll
      for (int nt = 0; nt < 4; ++nt)
#pragma unroll
        for (int rr = 0; rr < 2; ++rr)
          pw[nt * 2 + rr] =
              cvtpk_bf16(exp2_fast(S[nt][rr * 2]), exp2_fast(S[nt][rr * 2 + 1]));
    } else {
#pragma unroll
      for (int rr = 0; rr < 2; ++rr)
        pw[rr] = cvtpk_bf16(exp2_fast(S[0][rr * 2]), exp2_fast(S[0][rr * 2 + 1]));
#pragma unroll
      for (int i = 2; i < 8; ++i) pw[i] = 0u;
    }
    union PU { unsigned w[4]; bf16x8 v; };
    PU pk0, pk1;
#pragma unroll
    for (int i = 0; i < 4; ++i) { pk0.w[i] = pw[i]; pk1.w[i] = pw[4 + i]; }

    __builtin_amdgcn_s_setprio(1);
    // -- denominator: row sums via ones-MFMA (matrix pipe, not VALU) --
    Sden = __builtin_amdgcn_mfma_f32_16x16x32_bf16(pk0.v, ones, Sden, 0, 0, 0);
    Sden = __builtin_amdgcn_mfma_f32_16x16x32_bf16(pk1.v, ones, Sden, 0, 0, 0);

    // -- PV: B = V fragments from permuted-column Vt --
#pragma unroll
    for (int dt = 0; dt < 3; ++dt) {
      bf16x8 v0 = *(const bf16x8*)&Vt[cur][(dt * 16 + ll) * QS_STR + quad * 8];
      bf16x8 v1 = *(const bf16x8*)&Vt[cur][(dt * 16 + ll) * QS_STR + 32 + quad * 8];
      Ofr[dt] = __builtin_amdgcn_mfma_f32_16x16x32_bf16(pk0.v, v0, Ofr[dt], 0, 0, 0);
      Ofr[dt] = __builtin_amdgcn_mfma_f32_16x16x32_bf16(pk1.v, v1, Ofr[dt], 0, 0, 0);
    }
    __builtin_amdgcn_s_setprio(0);

    // -- land V regs into Vt[nxt] (auto vmcnt wait on vreg use) --
    if (t < 12 && wave < 6) {
      const u16* vp = (const u16*)&vreg;
#pragma unroll
      for (int j = 0; j < 8; ++j)
        Vt[nxt][(wave * 8 + j) * QS_STR + vcol] = vp[j];
    }
    // One barrier/iter: its vmcnt(0)+lgkmcnt(0) drain also retires the
    // K global_load_lds (in flight during the whole compute phase).
    __syncthreads();
  }

  // Sden[r] = denominator for qrow quad*4+r (same value in every ll lane).
  float inv[4];
#pragma unroll
  for (int r = 0; r < 4; ++r) inv[r] = 1.0f / Sden[r];
#pragma unroll
  for (int dt = 0; dt < 3; ++dt)
#pragma unroll
    for (int r = 0; r < 4; ++r) {
      int qrow = q0 + wave * 16 + quad * 4 + r;
      if (qrow < N_TOK)
        O[((size_t)b * N_TOK + qrow) * C_ + h * DH + dt * 16 + ll] =
            f2b(Ofr[dt][r] * inv[r]);
    }
}

// ---------------- Diagnostics ----------------
__global__ __launch_bounds__(256) void marker_fill(
    float* __restrict__ out, size_t n, float val) {
  size_t i = (size_t)blockIdx.x * 256 + threadIdx.x;
  const size_t stride = (size_t)gridDim.x * 256;
  for (; i < n; i += stride) out[i] = 0.f;
  if (blockIdx.x == 0 && threadIdx.x == 0) out[0] = val;
}

// ---------------- launch ----------------
extern "C" void kernel_launch(void* const* d_in, const int* in_sizes, int n_in,
                              void* d_out, int out_size, void* d_ws, size_t ws_size,
                              hipStream_t stream) {
  const float* x    = (const float*)d_in[0];
  const float* ln1w = (const float*)d_in[1];
  const float* ln1b = (const float*)d_in[2];
  const float* qw   = (const float*)d_in[3];
  const float* qb   = (const float*)d_in[4];
  const float* kw   = (const float*)d_in[5];
  const float* kb   = (const float*)d_in[6];
  const float* vw   = (const float*)d_in[7];
  const float* vb   = (const float*)d_in[8];
  const float* pw   = (const float*)d_in[9];
  const float* pb   = (const float*)d_in[10];
  const float* ln2w = (const float*)d_in[11];
  const float* ln2b = (const float*)d_in[12];
  const float* fc1w = (const float*)d_in[13];
  const float* fc1b = (const float*)d_in[14];
  const float* fc2w = (const float*)d_in[15];
  const float* fc2b = (const float*)d_in[16];

  const size_t BUF = (size_t)M1 * C_;
  float* outf = (float*)d_out;

  {
    static const int exp_sizes[19] = {
      M1 * C_, C_, C_, C_ * C_, C_, C_ * C_, C_, C_ * C_, C_, C_ * C_, C_,
      C_, C_, C_ * HID, HID, HID * C_, C_, 1, 1};
    int bad = -1;
    if (n_in != 19) bad = 99;
    else {
      for (int i = 0; i < 19; ++i)
        if (in_sizes[i] != exp_sizes[i]) { bad = i; break; }
    }
    if (bad >= 0) {
      marker_fill<<<1024, 256, 0, stream>>>(outf, BUF, 10000.0f + (float)bad);
      return;
    }
  }
  const size_t need_min  = 4096 + 3 * BUF * sizeof(u16);                     // 57.8 MB
  const size_t need_full = 4096 + (3 * BUF + (size_t)M1 * HID) * sizeof(u16); // 96.4 MB
  if (ws_size < need_min) {
    marker_fill<<<1024, 256, 0, stream>>>(outf, BUF, 30000.0f + (float)(ws_size >> 20));
    return;
  }
  const bool full_mlp = (ws_size >= need_full);

  u16* T0 = (u16*)((char*)d_ws + 4096);
  u16* T1 = T0 + BUF;
  u16* U  = T1 + BUF;
  u16* P  = U;
  u16* KB = U + (size_t)M2 * C_;
  u16* VB = U + (size_t)2 * M2 * C_;
  u16* HBq = U;                              // quarter-HB fallback overlay
  u16* HBfull = U + BUF;                     // full-M HB (only if full_mlp)
  u16* WTb = U + BUF - (size_t)(4 * C_ * C_ + 2 * C_ * HID);
  u16* wtq = WTb;
  u16* wtk = wtq + C_ * C_;
  u16* wtv = wtk + C_ * C_;
  u16* wtp = wtv + C_ * C_;
  u16* wtf1 = wtp + C_ * C_;
  u16* wtf2 = wtf1 + (size_t)C_ * HID;

  // 0+1. Fused LN1 + pool + all six weight transposes (one launch).
  {
    TransArgs ta;
    ta.src[0] = qw;   ta.dst[0] = wtq;  ta.K[0] = C_;  ta.N[0] = C_;
    ta.src[1] = kw;   ta.dst[1] = wtk;  ta.K[1] = C_;  ta.N[1] = C_;
    ta.src[2] = vw;   ta.dst[2] = wtv;  ta.K[2] = C_;  ta.N[2] = C_;
    ta.src[3] = pw;   ta.dst[3] = wtp;  ta.K[3] = C_;  ta.N[3] = C_;
    ta.src[4] = fc1w; ta.dst[4] = wtf1; ta.K[4] = C_;  ta.N[4] = HID;
    ta.src[5] = fc2w; ta.dst[5] = wtf2; ta.K[5] = HID; ta.N[5] = C_;
    ln1_pool_tr<<<TRB0 + 288, 256, 0, stream>>>(x, ln1w, ln1b, T0, P, ta);
  }

  // 2. Q/K/V projections, exact-work XCD-swizzled grid (882 blocks).
  {
    QKVArgs qa;
    qa.A[0] = T0; qa.BT[0] = wtq; qa.bias[0] = qb; qa.C[0] = T1;
    qa.A[1] = P;  qa.BT[1] = wtk; qa.bias[1] = kb; qa.C[1] = KB;
    qa.A[2] = P;  qa.BT[2] = wtv; qa.bias[2] = vb; qa.C[2] = VB;
    qa.osc[0] = 0.20823509507f;  // d^-0.5 * log2(e)
    qa.osc[1] = 1.0f;
    qa.osc[2] = 1.0f;
    gemm_qkv<<<dim3(882), 256, 0, stream>>>(qa);
  }

  // 3. MFMA flash attention -> T0  (1600 blocks, XCD-swizzled 1-D grid)
  attn_mfma<<<dim3(1600), 512, 0, stream>>>(T1, KB, VB, T0);

  // 4+5 fused. x1 = x + T0 @ pw + pb -> T1; LN2(x1) -> T0.
  proj_res_ln2<<<dim3(196), 512, 0, stream>>>(
      T0, wtp, pb, x, ln2w, ln2b, T1, T0);

  // 6/7. MLP. fc1: 128x128 (1176 blocks, 4.6/CU). fc2 (R22): BM=64 tile
  // -> 1176 blocks (was 588 = 2.3/CU, latency-exposed at K=768).
  if (full_mlp) {
    gemm_bt<1, false, false><<<dim3(1176), 256, 0, stream>>>(
        T0, wtf1, fc1b, nullptr, HBfull, HID, C_, 6);
    gemm_bt64<2, false, true><<<dim3(1176), 256, 0, stream>>>(
        HBfull, wtf2, fc2b, T1, outf, C_, HID, 3);
  } else {
    for (int qtr = 0; qtr < 4; ++qtr) {
      const size_t ro = (size_t)qtr * M1Q;
      gemm_bt<1, false, false><<<dim3(294), 256, 0, stream>>>(
          T0 + ro * C_, wtf1, fc1b, nullptr, HBq, HID, C_, 6);
      gemm_bt64<2, false, true><<<dim3(294), 256, 0, stream>>>(
          HBq, wtf2, fc2b, T1 + ro * C_, outf + ro * C_, C_, HID, 3);
    }
  }
}